// Round 8
// baseline (1009.005 us; speedup 1.0000x reference)
//
#include <hip/hip_runtime.h>
#include <math.h>

typedef unsigned short u16;
typedef unsigned int   u32;
typedef __attribute__((ext_vector_type(8))) short short8;
typedef __attribute__((ext_vector_type(4))) float f32x4;

typedef const void __attribute__((address_space(1))) gvoid_t;
typedef void       __attribute__((address_space(3))) svoid_t;

__device__ __forceinline__ void gload_lds16(const void* g, void* l){
    __builtin_amdgcn_global_load_lds((gvoid_t*)g, (svoid_t*)l, 16, 0, 0);
}

__device__ __forceinline__ float gelu_f(float x){
    return 0.5f * x * (1.0f + erff(x * 0.70710678118654752f));
}
__device__ __forceinline__ u16 f2b(float x){
    union{float f; u32 u;} v; v.f = x;
    u32 r = (v.u + 0x7fffu + ((v.u >> 16) & 1u)) >> 16;
    return (u16)r;
}
__device__ __forceinline__ float b2f(u16 h){
    union{u32 u; float f;} v; v.u = ((u32)h) << 16; return v.f;
}

// ===================== bf16 MFMA GEMM =====================
// A: bf16 [M][lda] row-major (k contiguous). B: bf16 [N][ldb] row-major (k contiguous).
// Tile 128x128, BK=64, 256 threads = 4 waves, each wave 64x64 (4x4 frags, 2 k-substeps).
// LDS per tile: row-major [128][64] bf16 (128B rows) with XOR swizzle:
//   slice slot s of row m holds data k8 = s ^ (m&7)  [G4 bank-conflict fix]
// Staged via global_load_lds(16B): linear LDS dest; inverse swizzle folded into
// per-lane GLOBAL address (rule #21). 8 lanes fetch one contiguous 128B row seg.
// Read side: slice (kk*4+g) of row m is at slot ((kk*4+g) ^ (mr&7)) -- sl[kk]
// precomputes this INCLUDING kk (sl[1] == sl[0]^32; do NOT re-XOR).
// EPI: 0:+bias->bf16  1:+bias,GELU->bf16  2:+bias->f32  3:/(rowv[r]+1e-8)->bf16
//      4:+bias+resid->f32  5:exp(acc-rowv[r])*scale->f32  6:exp(...)->bf16
//      8: plain f32 store into per-splitK slice (C += bz*sC)
template<int EPI, int GUARD, int CGUARD>
__global__ __launch_bounds__(256)
void gemm_bf16(const u16* __restrict__ A, int lda,
               const u16* __restrict__ B, int ldb,
               void* __restrict__ Cv, int ldc,
               const float* __restrict__ bias,
               const float* __restrict__ rowv,
               const float* __restrict__ resid,
               int Mrows, int Ncols, int K, int splitK,
               long sA, long sB, long sC, long sRV,
               float scale)
{
    const int bz = blockIdx.z;
    const int b  = bz / splitK, kc = bz % splitK;
    A += (long)b * sA;  B += (long)b * sB;
    const float* rv = (EPI == 3 || EPI == 5 || EPI == 6) ? rowv + (long)b * sRV : nullptr;

    __shared__ u16 As0[8192];   // [128][64] swizzled, 16KB
    __shared__ u16 Bs0[8192];
    __shared__ u16 As1[8192];
    __shared__ u16 Bs1[8192];

    const int tid = threadIdx.x;
    const int row0 = blockIdx.y * 128, col0 = blockIdx.x * 128;

    f32x4 acc[4][4] = {};

    const int l  = tid & 63, w4 = tid >> 6;
    const int wr = w4 >> 1, wc = w4 & 1;
    const int g  = l >> 4,  mr = l & 15;

    const int kLen   = K / splitK;
    const int kStart = kc * kLen;
    const int nt     = kLen / 64;

    // staging-side: LDS byte L = q*4096 + w4*1024 + l*16
    //   row m = q*32 + w4*8 + (l>>3); slot = l&7; stored k8 = (l&7) ^ (m&7)
    const int m0   = w4 * 8 + (l >> 3);          // 0..31 (+q*32)
    const int k8s  = (l & 7) ^ (m0 & 7);         // m&7 == (l>>3), q*32/w4*8 don't affect
    const int lBase = w4 * 512 + l * 8;          // u16 idx; + q*2048
    const u16* gA0 = A + (long)(row0 + m0) * lda + kStart + k8s * 8;
    const u16* gB0 = B + (long)(col0 + m0) * ldb + kStart + k8s * 8;

    // read-side per-thread constants (u16 idx)
    int aOff[4], bOff[4], sl[2];
    #pragma unroll
    for (int i = 0; i < 4; i++){
        aOff[i] = (wr * 64 + i * 16 + mr) * 64;
        bOff[i] = (wc * 64 + i * 16 + mr) * 64;
    }
    #pragma unroll
    for (int kk = 0; kk < 2; kk++)
        sl[kk] = (((kk * 4 + g) ^ (mr & 7)) & 7) * 8;   // includes kk term

#define STAGE(AS, BS, KOFF)                                             \
    {                                                                   \
        _Pragma("unroll")                                               \
        for (int q = 0; q < 4; q++){                                    \
            gload_lds16(gA0 + (long)q * 32 * lda + (KOFF), &(AS)[lBase + q * 2048]); \
            gload_lds16(gB0 + (long)q * 32 * ldb + (KOFF), &(BS)[lBase + q * 2048]); \
        }                                                               \
    }

#define COMPUTE(AS, BS)                                                 \
    {                                                                   \
        short8 af[2][4], bfr[2][4];                                     \
        _Pragma("unroll")                                               \
        for (int kk = 0; kk < 2; kk++){                                 \
            _Pragma("unroll")                                           \
            for (int i = 0; i < 4; i++){                                \
                af[kk][i]  = *(const short8*)&(AS)[aOff[i] + sl[kk]];   \
                bfr[kk][i] = *(const short8*)&(BS)[bOff[i] + sl[kk]];   \
            }                                                           \
        }                                                               \
        _Pragma("unroll")                                               \
        for (int kk = 0; kk < 2; kk++)                                  \
            _Pragma("unroll")                                           \
            for (int i = 0; i < 4; i++)                                 \
                _Pragma("unroll")                                       \
                for (int j = 0; j < 4; j++)                             \
                    acc[i][j] = __builtin_amdgcn_mfma_f32_16x16x32_bf16(af[kk][i], bfr[kk][j], acc[i][j], 0, 0, 0); \
    }

    // prologue
    STAGE(As0, Bs0, 0);

    for (int t = 0; t < nt; ){
        __syncthreads();
        if (t + 1 < nt) STAGE(As1, Bs1, (t + 1) * 64);
        COMPUTE(As0, Bs0);
        t++;
        if (t >= nt) break;
        __syncthreads();
        if (t + 1 < nt) STAGE(As0, Bs0, (t + 1) * 64);
        COMPUTE(As1, Bs1);
        t++;
    }
#undef STAGE
#undef COMPUTE

    float* Cf = (float*)Cv + (EPI == 8 ? (long)bz : (long)b) * sC;
    u16*   Cb = (u16*)Cv   + (long)b * sC;

    #pragma unroll
    for (int i = 0; i < 4; i++){
        #pragma unroll
        for (int j = 0; j < 4; j++){
            const int col = col0 + wc * 64 + j * 16 + mr;
            if (CGUARD && col >= Ncols) continue;
            float bv = 0.f;
            if (EPI == 0 || EPI == 1 || EPI == 2 || EPI == 4) bv = bias[col];
            #pragma unroll
            for (int r = 0; r < 4; r++){
                const int row = row0 + wr * 64 + i * 16 + g * 4 + r;
                if (GUARD && row >= Mrows) continue;
                float vv = acc[i][j][r];
                if      (EPI == 1){ vv += bv; vv = gelu_f(vv); }
                else if (EPI == 3){ vv = vv / (rv[row] + 1e-8f); }
                else if (EPI == 4){ vv += bv + resid[(long)row * ldc + col]; }
                else if (EPI == 5 || EPI == 6){ vv = expf(vv - rv[row]) * scale; }
                else if (EPI == 8){ }
                else              { vv += bv; }
                if (EPI == 2 || EPI == 4 || EPI == 5 || EPI == 8) Cf[(long)row * ldc + col] = vv;
                else                                               Cb[(long)row * ldc + col] = f2b(vv);
            }
        }
    }
}

// tiled transpose: in f32 [R][C] -> out bf16 [C][R]; grid (C/64, R/64), 256 thr
__global__ __launch_bounds__(256)
void tr_kernel(const float* __restrict__ in, u16* __restrict__ out, long R, int C)
{
    __shared__ float t[64][65];
    const long cb = (long)blockIdx.x * 64, rb = (long)blockIdx.y * 64;
    const int tl = threadIdx.x & 63, tw = threadIdx.x >> 6;
    #pragma unroll
    for (int i = 0; i < 16; i++){
        const int r = tw + i * 4;
        t[r][tl] = in[(rb + r) * C + cb + tl];
    }
    __syncthreads();
    #pragma unroll
    for (int i = 0; i < 16; i++){
        const int c = tw + i * 4;
        out[(cb + c) * R + rb + tl] = f2b(t[tl][c]);
    }
}

// kptvb[b][i] = bf16( sum_{kc<7} kptv_all[b*7+kc][i] )
__global__ __launch_bounds__(256)
void kred_kernel(const float* __restrict__ in, u16* __restrict__ out, long n)
{
    long idx = (long)blockIdx.x * 256 + threadIdx.x;
    if (idx >= n) return;
    const long b = idx / 73728, r = idx - b * 73728;
    const float* s = in + b * 7 * 73728L + r;
    float acc = 0.f;
    #pragma unroll
    for (int kc = 0; kc < 7; kc++) acc += s[kc * 73728L];
    out[idx] = f2b(acc);
}

// LayerNorm over D=384 (f32 in); optional f32 and bf16 outputs.
__global__ __launch_bounds__(256)
void ln_kernel(const float* __restrict__ x, float* __restrict__ of, u16* __restrict__ ob,
               const float* __restrict__ g, const float* __restrict__ bta)
{
    const int lane = threadIdx.x & 63;
    const long r = (long)blockIdx.x * 4 + (threadIdx.x >> 6);
    const float* xr = x + r * 384;
    float v[6]; float s = 0.f;
    #pragma unroll
    for (int i = 0; i < 6; i++){ v[i] = xr[lane + i*64]; s += v[i]; }
    #pragma unroll
    for (int off = 32; off; off >>= 1) s += __shfl_xor(s, off);
    const float mu = s * (1.0f/384.0f);
    float q = 0.f;
    #pragma unroll
    for (int i = 0; i < 6; i++){ float d = v[i] - mu; q += d*d; }
    #pragma unroll
    for (int off = 32; off; off >>= 1) q += __shfl_xor(q, off);
    const float inv = rsqrtf(q * (1.0f/384.0f) + 1e-5f);
    #pragma unroll
    for (int i = 0; i < 6; i++){
        const int c = lane + i*64;
        const float val = (v[i] - mu) * inv * g[c] + bta[c];
        if (of) of[r * 384 + c] = val;
        if (ob) ob[r * 384 + c] = f2b(val);
    }
}

// xd[r] = 0.5*||x_row||^2 over 384 bf16 cols
__global__ __launch_bounds__(256)
void xd_b_kernel(const u16* __restrict__ x, float* __restrict__ xd)
{
    const int lane = threadIdx.x & 63;
    const long r = (long)blockIdx.x * 4 + (threadIdx.x >> 6);
    const u16* xr = x + r * 384;
    float s = 0.f;
    #pragma unroll
    for (int i = 0; i < 6; i++){ float a = b2f(xr[lane + i*64]); s += a*a; }
    #pragma unroll
    for (int off = 32; off; off >>= 1) s += __shfl_xor(s, off);
    if (lane == 0) xd[r] = 0.5f * s;
}

// Dn[r] = dot(qp_bf16[r,:192], kpsum[r/T,:192])
__global__ __launch_bounds__(256)
void dn_kernel(const u16* __restrict__ qp, const float* __restrict__ kpsum,
               float* __restrict__ Dn, int T)
{
    const int lane = threadIdx.x & 63;
    const long r = (long)blockIdx.x * 4 + (threadIdx.x >> 6);
    const int b = (int)(r / T);
    const u16* qr = qp + r * 192;
    const float* ks = kpsum + (long)b * 192;
    float s = 0.f;
    #pragma unroll
    for (int i = 0; i < 3; i++){ const int m = lane + i*64; s += b2f(qr[m]) * ks[m]; }
    #pragma unroll
    for (int off = 32; off; off >>= 1) s += __shfl_xor(s, off);
    if (lane == 0) Dn[r] = s;
}

__global__ __launch_bounds__(192)
void kpsum_kernel(const float* __restrict__ kp, float* __restrict__ kpsum)
{
    const int b = blockIdx.x, ch = blockIdx.y, m = threadIdx.x;
    const float* base = kp + ((long)b * 3136 + (long)ch * 448) * 192 + m;
    float s = 0.f;
    for (int t = 0; t < 448; t++) s += base[(long)t * 192];
    atomicAdd(&kpsum[b * 192 + m], s);
}

__global__ __launch_bounds__(256)
void zero_kernel(float* __restrict__ p, long n)
{
    long i = (long)blockIdx.x * 256 + threadIdx.x;
    long stride = (long)gridDim.x * 256;
    for (; i < n; i += stride) p[i] = 0.f;
}

// concat(in1,in2) row-major -> bf16 [Mc][768]
__global__ __launch_bounds__(256)
void ca_kernel(const float* __restrict__ i1, const float* __restrict__ i2,
               u16* __restrict__ a0, long nquad)
{
    long idx = (long)blockIdx.x * 256 + threadIdx.x;
    if (idx >= nquad) return;
    const long r = idx / 192;
    const int  c0 = (int)(idx % 192) * 4;
    const float* src = (c0 < 384) ? &i1[r * 384 + c0] : &i2[r * 384 + (c0 - 384)];
    float4 v = *(const float4*)src;
    u32 w0 = (u32)f2b(v.x) | ((u32)f2b(v.y) << 16);
    u32 w1 = (u32)f2b(v.z) | ((u32)f2b(v.w) << 16);
    *(uint2*)&a0[r * 768 + c0] = make_uint2(w0, w1);
}

// wt[n*K + k] = bf16(w[k*N + n])
__global__ __launch_bounds__(256)
void wt_kernel(const float* __restrict__ w, u16* __restrict__ wt, int K, int N, long total)
{
    long idx = (long)blockIdx.x * 256 + threadIdx.x;
    if (idx >= total) return;
    const long n = idx / K, k = idx - n * K;
    wt[idx] = f2b(w[k * N + n]);
}

// flat f32 -> bf16
__global__ __launch_bounds__(256)
void cvt_kernel(const float* __restrict__ s, u16* __restrict__ d, long n4)
{
    long idx = (long)blockIdx.x * 256 + threadIdx.x;
    if (idx >= n4) return;
    float4 v = *(const float4*)&s[idx * 4];
    u32 w0 = (u32)f2b(v.x) | ((u32)f2b(v.y) << 16);
    u32 w1 = (u32)f2b(v.z) | ((u32)f2b(v.w) << 16);
    *(uint2*)&d[idx * 4] = make_uint2(w0, w1);
}

extern "C" void kernel_launch(void* const* d_in, const int* in_sizes, int n_in,
                              void* d_out, int out_size, void* d_ws, size_t ws_size,
                              hipStream_t stream)
{
    const long T = 3136;
    const float prm_scale = 0.07216878364870322f;  // 1/sqrt(192)

    const float* in1    = (const float*)d_in[0];
    const float* in2    = (const float*)d_in[1];
    const float* W1     = (const float*)d_in[2];
    const float* b1     = (const float*)d_in[3];
    const float* W2     = (const float*)d_in[4];
    const float* b2     = (const float*)d_in[5];
    const float* kqv_w  = (const float*)d_in[6];
    const float* kqv_b  = (const float*)d_in[7];
    const float* proj_w = (const float*)d_in[8];
    const float* proj_b = (const float*)d_in[9];
    const float* ln1_g  = (const float*)d_in[10];
    const float* ln1_b  = (const float*)d_in[11];
    const float* ln2_g  = (const float*)d_in[12];
    const float* ln2_b  = (const float*)d_in[13];
    const float* mlp_w1 = (const float*)d_in[14];
    const float* mlp_b1 = (const float*)d_in[15];
    const float* mlp_w2 = (const float*)d_in[16];
    const float* mlp_b2 = (const float*)d_in[17];
    const float* w_prm  = (const float*)d_in[18];
    float* out = (float*)d_out;

    // ---- workspace layout ----
    char* p = (char*)d_ws;
    auto alloc = [&](long bytes)->char*{ char* r = p; p += (bytes + 255) & ~255L; return r; };

    // chunk-invariant bf16 weights
    u16* w1t   = (u16*)alloc(294912L * 2);   // [384][768]
    u16* w2t   = (u16*)alloc(147456L * 2);   // [384][384]
    u16* kqvt  = (u16*)alloc(442368L * 2);   // [1152][384]
    u16* prjt  = (u16*)alloc(147456L * 2);
    u16* m1t   = (u16*)alloc(147456L * 2);
    u16* m2t   = (u16*)alloc(147456L * 2);
    u16* wprmb = (u16*)alloc(256L * 384 * 2); // [256 pad][384], rows 192+ zeroed
    char* chunkBase = p;

    // per-batch ws bytes (see allocs below)
    const long perBatch = 2752L * T * 2 + 962L * T * 4
                        + (192L + 7L * 73728L) * 4 + 73728L * 2;
    const long fixed = (long)(chunkBase - (char*)d_ws) + (1L << 20);
    int nb = 2;
    for (int cand = 16; cand >= 2; cand >>= 1){
        if (fixed + (long)cand * perBatch + 128L * 1024 <= (long)ws_size){ nb = cand; break; }
    }

    const dim3 blk(256);

    // weight transpose/convert (idempotent per call)
    wt_kernel<<<dim3((294912 + 255) / 256), blk, 0, stream>>>(W1, w1t, 768, 384, 294912);
    wt_kernel<<<dim3((147456 + 255) / 256), blk, 0, stream>>>(W2, w2t, 384, 384, 147456);
    wt_kernel<<<dim3((442368 + 255) / 256), blk, 0, stream>>>(kqv_w, kqvt, 384, 1152, 442368);
    wt_kernel<<<dim3((147456 + 255) / 256), blk, 0, stream>>>(proj_w, prjt, 384, 384, 147456);
    wt_kernel<<<dim3((147456 + 255) / 256), blk, 0, stream>>>(mlp_w1, m1t, 384, 384, 147456);
    wt_kernel<<<dim3((147456 + 255) / 256), blk, 0, stream>>>(mlp_w2, m2t, 384, 384, 147456);
    zero_kernel<<<dim3(64), blk, 0, stream>>>((float*)wprmb, 256L * 384 / 2);
    cvt_kernel<<<dim3((18432 + 255) / 256), blk, 0, stream>>>(w_prm, wprmb, 18432);

    for (int b0 = 0; b0 < 16; b0 += nb){
        const long Mc = (long)nb * T;
        const int  gy128 = (int)(Mc / 128);
        const float* i1 = in1 + (long)b0 * T * 384;
        const float* i2 = in2 + (long)b0 * T * 384;
        float* outc = out + (long)b0 * T * 384;

        p = chunkBase;
        u16*  a0    = (u16*)alloc(Mc * 768 * 2);   // concat bf16 ; later mlp hidden
        u16*  h1b   = (u16*)alloc(Mc * 384 * 2);   // h1 bf16 ; later t_att bf16
        u16*  xnb   = (u16*)alloc(Mc * 384 * 2);   // xn bf16 ; later z bf16
        u16*  qpb   = (u16*)alloc(Mc * 192 * 2);   // qp bf16 (followed by allocs: OOB-read pad)
        u16*  kqb   = (u16*)alloc(Mc * 384 * 2);   // k bf16, then q bf16
        u16*  vT    = (u16*)alloc(384L * Mc * 2);  // v transposed bf16 [384][Mc]
        u16*  kpT   = (u16*)alloc(256L * Mc * 2);  // kp transposed bf16 [256 pad][Mc]
        float* xf   = (float*)alloc(Mc * 384 * 4); // x f32
        float* vf   = (float*)alloc(Mc * 384 * 4); // v f32
        float* kp   = (float*)alloc(Mc * 192 * 4); // kp f32
        float* xdv  = (float*)alloc(Mc * 4);
        float* Dn   = (float*)alloc(Mc * 4);
        float* kpsum= (float*)alloc((long)nb * 192 * 4);
        float* kptvA= (float*)alloc((long)nb * 7 * 73728 * 4);  // split-K slices
        u16*  kptvb = (u16*)alloc((long)nb * 73728 * 2);
        (void)alloc(128L * 1024);                   // tail pad

        // 0) a0 = bf16(concat)
        {
            long nq = Mc * 192;
            ca_kernel<<<dim3((unsigned)((nq + 255) / 256)), blk, 0, stream>>>(i1, i2, a0, nq);
        }
        // 1) h1 = GELU(a0 @ W1t^T + b1)  [bf16]
        gemm_bf16<1,0,0><<<dim3(3, gy128, 1), blk, 0, stream>>>(
            a0, 768, w1t, 768, h1b, 384, b1, nullptr, nullptr,
            (int)Mc, 384, 768, 1, 0,0,0,0, 0.f);
        // 2) x = h1 @ W2t^T + b2  [f32]
        gemm_bf16<2,0,0><<<dim3(3, gy128, 1), blk, 0, stream>>>(
            h1b, 384, w2t, 384, xf, 384, b2, nullptr, nullptr,
            (int)Mc, 384, 384, 1, 0,0,0,0, 0.f);
        // 3) LN1 -> xn bf16
        ln_kernel<<<dim3((unsigned)(Mc / 4)), blk, 0, stream>>>(xf, nullptr, xnb, ln1_g, ln1_b);
        // 4) k = xn @ kqvt[0:384] + b  [bf16]
        gemm_bf16<0,0,0><<<dim3(3, gy128, 1), blk, 0, stream>>>(
            xnb, 384, kqvt, 384, kqb, 384, kqv_b, nullptr, nullptr,
            (int)Mc, 384, 384, 1, 0,0,0,0, 0.f);
        xd_b_kernel<<<dim3((unsigned)(Mc / 4)), blk, 0, stream>>>(kqb, xdv);
        // 5) kp = exp(k @ wprm^T - xd)*scale  [f32, N=192 col-guarded]
        gemm_bf16<5,0,1><<<dim3(2, gy128, 1), blk, 0, stream>>>(
            kqb, 384, wprmb, 384, kp, 192, nullptr, xdv, nullptr,
            (int)Mc, 192, 384, 1, 0,0,0,0, prm_scale);
        // 6) kpsum
        zero_kernel<<<dim3(2), blk, 0, stream>>>(kpsum, (long)nb * 192);
        kpsum_kernel<<<dim3(nb, 7, 1), dim3(192), 0, stream>>>(kp, kpsum);
        // 7) q (overwrites kqb; kp GEMM already consumed k)
        gemm_bf16<0,0,0><<<dim3(3, gy128, 1), blk, 0, stream>>>(
            xnb, 384, kqvt + 384L * 384, 384, kqb, 384, kqv_b + 384, nullptr, nullptr,
            (int)Mc, 384, 384, 1, 0,0,0,0, 0.f);
        xd_b_kernel<<<dim3((unsigned)(Mc / 4)), blk, 0, stream>>>(kqb, xdv);
        gemm_bf16<6,0,1><<<dim3(2, gy128, 1), blk, 0, stream>>>(
            kqb, 384, wprmb, 384, qpb, 192, nullptr, xdv, nullptr,
            (int)Mc, 192, 384, 1, 0,0,0,0, prm_scale);
        // 8) v = xn @ kqvt[768:] + b  [f32]
        gemm_bf16<2,0,0><<<dim3(3, gy128, 1), blk, 0, stream>>>(
            xnb, 384, kqvt + 768L * 384, 384, vf, 384, kqv_b + 768, nullptr, nullptr,
            (int)Mc, 384, 384, 1, 0,0,0,0, 0.f);
        // 9) transposes: vf -> vT [384][Mc], kp -> kpT [192(256)][Mc]
        tr_kernel<<<dim3(6, (unsigned)(Mc / 64)), blk, 0, stream>>>(vf, vT, Mc, 384);
        tr_kernel<<<dim3(3, (unsigned)(Mc / 64)), blk, 0, stream>>>(kp, kpT, Mc, 192);
        // 10) kptv MFMA: [384][192] = vT(slice b) @ kpT(slice b)^T, split-K=7 slices
        gemm_bf16<8,0,1><<<dim3(2, 3, nb * 7), blk, 0, stream>>>(
            vT, (int)Mc, kpT, (int)Mc, kptvA, 192, nullptr, nullptr, nullptr,
            384, 192, 3136, 7, 3136, 3136, 73728, 0, 0.f);
        kred_kernel<<<dim3((unsigned)((long)nb * 73728 / 256)), blk, 0, stream>>>(
            kptvA, kptvb, (long)nb * 73728);
        // 11) Dn
        dn_kernel<<<dim3((unsigned)(Mc / 4)), blk, 0, stream>>>(qpb, kpsum, Dn, (int)T);
        // 12) t_att = (qp @ kptv^T) / (Dn+1e-8)  [bf16, per-batch, row-guarded]
        gemm_bf16<3,1,0><<<dim3(3, 25, nb), blk, 0, stream>>>(
            qpb, 192, kptvb, 192, h1b, 384, nullptr, Dn, nullptr,
            (int)T, 384, 192, 1, T*192, 73728, T*384, T, 0.f);
        // 13) y = t_att @ proj + proj_b + v  -> outc (f32)
        gemm_bf16<4,0,0><<<dim3(3, gy128, 1), blk, 0, stream>>>(
            h1b, 384, prjt, 384, outc, 384, proj_b, nullptr, vf,
            (int)Mc, 384, 384, 1, 0,0,0,0, 0.f);
        // 14) LN2 -> z bf16
        ln_kernel<<<dim3((unsigned)(Mc / 4)), blk, 0, stream>>>(outc, nullptr, xnb, ln2_g, ln2_b);
        // 15) h = GELU(z @ mlp1 + b)  [bf16] -> a0 region
        gemm_bf16<1,0,0><<<dim3(3, gy128, 1), blk, 0, stream>>>(
            xnb, 384, m1t, 384, a0, 384, mlp_b1, nullptr, nullptr,
            (int)Mc, 384, 384, 1, 0,0,0,0, 0.f);
        // 16) out = h @ mlp2 + b + y  (in-place residual on outc)
        gemm_bf16<4,0,0><<<dim3(3, gy128, 1), blk, 0, stream>>>(
            a0, 384, m2t, 384, outc, 384, mlp_b2, nullptr, outc,
            (int)Mc, 384, 384, 1, 0,0,0,0, 0.f);
    }
}

// Round 9
// 961.467 us; speedup vs baseline: 1.0494x; 1.0494x over previous
//
#include <hip/hip_runtime.h>
#include <math.h>

typedef unsigned short u16;
typedef unsigned int   u32;
typedef __attribute__((ext_vector_type(8))) short short8;
typedef __attribute__((ext_vector_type(4))) float f32x4;

typedef const void __attribute__((address_space(1))) gvoid_t;
typedef void       __attribute__((address_space(3))) svoid_t;

__device__ __forceinline__ void gload_lds16(const void* g, void* l){
    __builtin_amdgcn_global_load_lds((gvoid_t*)g, (svoid_t*)l, 16, 0, 0);
}

__device__ __forceinline__ float gelu_f(float x){
    return 0.5f * x * (1.0f + erff(x * 0.70710678118654752f));
}
__device__ __forceinline__ u16 f2b(float x){
    union{float f; u32 u;} v; v.f = x;
    u32 r = (v.u + 0x7fffu + ((v.u >> 16) & 1u)) >> 16;
    return (u16)r;
}
__device__ __forceinline__ float b2f(u16 h){
    union{u32 u; float f;} v; v.u = ((u32)h) << 16; return v.f;
}

// ===================== bf16 MFMA GEMM (frozen core from round 8) =====================
// A: bf16 [M][lda] row-major. B: bf16 [N][ldb] row-major. Tile 128x128, BK=64,
// 4 waves, XOR-swizzled LDS ([128][64], slot s of row m holds k8 = s^(m&7)),
// staged by global_load_lds(16B) with inverse swizzle folded into global addr.
// EPI: 0:+bias->bf16  1:+bias,GELU->bf16  2:+bias->f32  3:/(rowv[r]+1e-8)->bf16
//      4:+bias+resid(f32,ldr)->f32  6:exp(acc-rowv[r])*scale->bf16
//      7:exp(acc-rowv[r])*scale->bf16 TRANSPOSED store C[col*ldc+row]
//      8:plain f32 store into per-splitK slice (C += bz*sC)
//      9:+bias+resid(bf16,ldr)->f32
template<int EPI, int GUARD, int CGUARD>
__global__ __launch_bounds__(256)
void gemm_bf16(const u16* __restrict__ A, int lda,
               const u16* __restrict__ B, int ldb,
               void* __restrict__ Cv, int ldc,
               const float* __restrict__ bias,
               const float* __restrict__ rowv,
               const void* __restrict__ resid, int ldr,
               int Mrows, int Ncols, int K, int splitK,
               long sA, long sB, long sC, long sRV,
               float scale)
{
    const int bz = blockIdx.z;
    const int b  = bz / splitK, kc = bz % splitK;
    A += (long)b * sA;  B += (long)b * sB;
    const float* rv = (EPI == 3 || EPI == 6 || EPI == 7) ? rowv + (long)b * sRV : nullptr;

    __shared__ u16 As0[8192];
    __shared__ u16 Bs0[8192];
    __shared__ u16 As1[8192];
    __shared__ u16 Bs1[8192];

    const int tid = threadIdx.x;
    const int row0 = blockIdx.y * 128, col0 = blockIdx.x * 128;

    f32x4 acc[4][4] = {};

    const int l  = tid & 63, w4 = tid >> 6;
    const int wr = w4 >> 1, wc = w4 & 1;
    const int g  = l >> 4,  mr = l & 15;

    const int kLen   = K / splitK;
    const int kStart = kc * kLen;
    const int nt     = kLen / 64;

    const int m0   = w4 * 8 + (l >> 3);
    const int k8s  = (l & 7) ^ (m0 & 7);
    const int lBase = w4 * 512 + l * 8;
    const u16* gA0 = A + (long)(row0 + m0) * lda + kStart + k8s * 8;
    const u16* gB0 = B + (long)(col0 + m0) * ldb + kStart + k8s * 8;

    int aOff[4], bOff[4], sl[2];
    #pragma unroll
    for (int i = 0; i < 4; i++){
        aOff[i] = (wr * 64 + i * 16 + mr) * 64;
        bOff[i] = (wc * 64 + i * 16 + mr) * 64;
    }
    #pragma unroll
    for (int kk = 0; kk < 2; kk++)
        sl[kk] = (((kk * 4 + g) ^ (mr & 7)) & 7) * 8;

#define STAGE(AS, BS, KOFF)                                             \
    {                                                                   \
        _Pragma("unroll")                                               \
        for (int q = 0; q < 4; q++){                                    \
            gload_lds16(gA0 + (long)q * 32 * lda + (KOFF), &(AS)[lBase + q * 2048]); \
            gload_lds16(gB0 + (long)q * 32 * ldb + (KOFF), &(BS)[lBase + q * 2048]); \
        }                                                               \
    }

#define COMPUTE(AS, BS)                                                 \
    {                                                                   \
        short8 af[2][4], bfr[2][4];                                     \
        _Pragma("unroll")                                               \
        for (int kk = 0; kk < 2; kk++){                                 \
            _Pragma("unroll")                                           \
            for (int i = 0; i < 4; i++){                                \
                af[kk][i]  = *(const short8*)&(AS)[aOff[i] + sl[kk]];   \
                bfr[kk][i] = *(const short8*)&(BS)[bOff[i] + sl[kk]];   \
            }                                                           \
        }                                                               \
        _Pragma("unroll")                                               \
        for (int kk = 0; kk < 2; kk++)                                  \
            _Pragma("unroll")                                           \
            for (int i = 0; i < 4; i++)                                 \
                _Pragma("unroll")                                       \
                for (int j = 0; j < 4; j++)                             \
                    acc[i][j] = __builtin_amdgcn_mfma_f32_16x16x32_bf16(af[kk][i], bfr[kk][j], acc[i][j], 0, 0, 0); \
    }

    STAGE(As0, Bs0, 0);

    for (int t = 0; t < nt; ){
        __syncthreads();
        if (t + 1 < nt) STAGE(As1, Bs1, (t + 1) * 64);
        COMPUTE(As0, Bs0);
        t++;
        if (t >= nt) break;
        __syncthreads();
        if (t + 1 < nt) STAGE(As0, Bs0, (t + 1) * 64);
        COMPUTE(As1, Bs1);
        t++;
    }
#undef STAGE
#undef COMPUTE

    float* Cf = (float*)Cv + (EPI == 8 ? (long)bz : (long)b) * sC;
    u16*   Cb = (u16*)Cv   + (long)b * sC;

    #pragma unroll
    for (int i = 0; i < 4; i++){
        #pragma unroll
        for (int j = 0; j < 4; j++){
            const int col = col0 + wc * 64 + j * 16 + mr;
            if (CGUARD && col >= Ncols) continue;
            if (EPI == 7){
                const int rowb = row0 + wr * 64 + i * 16 + g * 4;
                u16 pk[4];
                #pragma unroll
                for (int r = 0; r < 4; r++)
                    pk[r] = f2b(expf(acc[i][j][r] - rv[rowb + r]) * scale);
                *(ushort4*)&Cb[(long)col * ldc + rowb] = *(ushort4*)pk;
            } else {
                float bv = 0.f;
                if (EPI == 0 || EPI == 1 || EPI == 2 || EPI == 4 || EPI == 9) bv = bias[col];
                #pragma unroll
                for (int r = 0; r < 4; r++){
                    const int row = row0 + wr * 64 + i * 16 + g * 4 + r;
                    if (GUARD && row >= Mrows) continue;
                    float vv = acc[i][j][r];
                    if      (EPI == 1){ vv += bv; vv = gelu_f(vv); }
                    else if (EPI == 3){ vv = vv / (rv[row] + 1e-8f); }
                    else if (EPI == 4){ vv += bv + ((const float*)resid)[(long)row * ldr + col]; }
                    else if (EPI == 6){ vv = expf(vv - rv[row]) * scale; }
                    else if (EPI == 8){ }
                    else if (EPI == 9){ vv += bv + b2f(((const u16*)resid)[(long)row * ldr + col]); }
                    else              { vv += bv; }
                    if (EPI == 2 || EPI == 4 || EPI == 8 || EPI == 9) Cf[(long)row * ldc + col] = vv;
                    else                                              Cb[(long)row * ldc + col] = f2b(vv);
                }
            }
        }
    }
}

// bf16 strided transpose: out[(cb+c)*R + rb+r] = in[(rb+r)*inStride + cb+c]
__global__ __launch_bounds__(256)
void trb_kernel(const u16* __restrict__ in, long inStride, u16* __restrict__ out, long R)
{
    __shared__ u16 t[64][72];
    const long cb = (long)blockIdx.x * 64, rb = (long)blockIdx.y * 64;
    const int tl = threadIdx.x & 63, tw = threadIdx.x >> 6;
    #pragma unroll
    for (int i = 0; i < 16; i++){
        const int r = tw + i * 4;
        t[r][tl] = in[(rb + r) * inStride + cb + tl];
    }
    __syncthreads();
    #pragma unroll
    for (int i = 0; i < 16; i++){
        const int c = tw + i * 4;
        out[(cb + c) * R + rb + tl] = t[tl][c];
    }
}

// kptvb[b][i] = bf16( sum_{kc<7} kptv_all[b*7+kc][i] )
__global__ __launch_bounds__(256)
void kred_kernel(const float* __restrict__ in, u16* __restrict__ out, long n)
{
    long idx = (long)blockIdx.x * 256 + threadIdx.x;
    if (idx >= n) return;
    const long b = idx / 73728, r = idx - b * 73728;
    const float* s = in + b * 7 * 73728L + r;
    float acc = 0.f;
    #pragma unroll
    for (int kc = 0; kc < 7; kc++) acc += s[kc * 73728L];
    out[idx] = f2b(acc);
}

// LayerNorm over D=384 (f32 in); optional f32 and bf16 outputs.
__global__ __launch_bounds__(256)
void ln_kernel(const float* __restrict__ x, float* __restrict__ of, u16* __restrict__ ob,
               const float* __restrict__ g, const float* __restrict__ bta)
{
    const int lane = threadIdx.x & 63;
    const long r = (long)blockIdx.x * 4 + (threadIdx.x >> 6);
    const float* xr = x + r * 384;
    float v[6]; float s = 0.f;
    #pragma unroll
    for (int i = 0; i < 6; i++){ v[i] = xr[lane + i*64]; s += v[i]; }
    #pragma unroll
    for (int off = 32; off; off >>= 1) s += __shfl_xor(s, off);
    const float mu = s * (1.0f/384.0f);
    float q = 0.f;
    #pragma unroll
    for (int i = 0; i < 6; i++){ float d = v[i] - mu; q += d*d; }
    #pragma unroll
    for (int off = 32; off; off >>= 1) q += __shfl_xor(q, off);
    const float inv = rsqrtf(q * (1.0f/384.0f) + 1e-5f);
    #pragma unroll
    for (int i = 0; i < 6; i++){
        const int c = lane + i*64;
        const float val = (v[i] - mu) * inv * g[c] + bta[c];
        if (of) of[r * 384 + c] = val;
        if (ob) ob[r * 384 + c] = f2b(val);
    }
}

// xd[r] = 0.5*||x_row||^2 over 384 bf16 cols, row stride `stride`
__global__ __launch_bounds__(256)
void xd_b_kernel(const u16* __restrict__ x, long stride, float* __restrict__ xd)
{
    const int lane = threadIdx.x & 63;
    const long r = (long)blockIdx.x * 4 + (threadIdx.x >> 6);
    const u16* xr = x + r * stride;
    float s = 0.f;
    #pragma unroll
    for (int i = 0; i < 6; i++){ float a = b2f(xr[lane + i*64]); s += a*a; }
    #pragma unroll
    for (int off = 32; off; off >>= 1) s += __shfl_xor(s, off);
    if (lane == 0) xd[r] = 0.5f * s;
}

// Dn[r] = dot(qp_bf16[r,:192], kpsum[r/T,:192])
__global__ __launch_bounds__(256)
void dn_kernel(const u16* __restrict__ qp, const float* __restrict__ kpsum,
               float* __restrict__ Dn, int T)
{
    const int lane = threadIdx.x & 63;
    const long r = (long)blockIdx.x * 4 + (threadIdx.x >> 6);
    const int b = (int)(r / T);
    const u16* qr = qp + r * 192;
    const float* ks = kpsum + (long)b * 192;
    float s = 0.f;
    #pragma unroll
    for (int i = 0; i < 3; i++){ const int m = lane + i*64; s += b2f(qr[m]) * ks[m]; }
    #pragma unroll
    for (int off = 32; off; off >>= 1) s += __shfl_xor(s, off);
    if (lane == 0) Dn[r] = s;
}

// kpsum[bl][m] = sum_t kpT[m][bl*T + t]   (one wave per (m,bl); no atomics)
__global__ __launch_bounds__(256)
void kpsum2_kernel(const u16* __restrict__ kpT, float* __restrict__ kpsum, long Mc, int T)
{
    const int lane = threadIdx.x & 63;
    const int gw = blockIdx.x * 4 + (threadIdx.x >> 6);
    const int m = gw % 192, bl = gw / 192;
    const u16* row = kpT + (long)m * Mc + (long)bl * T;
    float s = 0.f;
    for (int i = lane; i < T; i += 64) s += b2f(row[i]);
    #pragma unroll
    for (int off = 32; off; off >>= 1) s += __shfl_xor(s, off);
    if (lane == 0) kpsum[bl * 192 + m] = s;
}

__global__ __launch_bounds__(256)
void zero_kernel(float* __restrict__ p, long n)
{
    long i = (long)blockIdx.x * 256 + threadIdx.x;
    long stride = (long)gridDim.x * 256;
    for (; i < n; i += stride) p[i] = 0.f;
}

// concat(in1,in2) row-major -> bf16 [Mc][768]
__global__ __launch_bounds__(256)
void ca_kernel(const float* __restrict__ i1, const float* __restrict__ i2,
               u16* __restrict__ a0, long nquad)
{
    long idx = (long)blockIdx.x * 256 + threadIdx.x;
    if (idx >= nquad) return;
    const long r = idx / 192;
    const int  c0 = (int)(idx % 192) * 4;
    const float* src = (c0 < 384) ? &i1[r * 384 + c0] : &i2[r * 384 + (c0 - 384)];
    float4 v = *(const float4*)src;
    u32 w0 = (u32)f2b(v.x) | ((u32)f2b(v.y) << 16);
    u32 w1 = (u32)f2b(v.z) | ((u32)f2b(v.w) << 16);
    *(uint2*)&a0[r * 768 + c0] = make_uint2(w0, w1);
}

// wt[n*K + k] = bf16(w[k*N + n])
__global__ __launch_bounds__(256)
void wt_kernel(const float* __restrict__ w, u16* __restrict__ wt, int K, int N, long total)
{
    long idx = (long)blockIdx.x * 256 + threadIdx.x;
    if (idx >= total) return;
    const long n = idx / K, k = idx - n * K;
    wt[idx] = f2b(w[k * N + n]);
}

// flat f32 -> bf16
__global__ __launch_bounds__(256)
void cvt_kernel(const float* __restrict__ s, u16* __restrict__ d, long n4)
{
    long idx = (long)blockIdx.x * 256 + threadIdx.x;
    if (idx >= n4) return;
    float4 v = *(const float4*)&s[idx * 4];
    u32 w0 = (u32)f2b(v.x) | ((u32)f2b(v.y) << 16);
    u32 w1 = (u32)f2b(v.z) | ((u32)f2b(v.w) << 16);
    *(uint2*)&d[idx * 4] = make_uint2(w0, w1);
}

extern "C" void kernel_launch(void* const* d_in, const int* in_sizes, int n_in,
                              void* d_out, int out_size, void* d_ws, size_t ws_size,
                              hipStream_t stream)
{
    const long T = 3136;
    const float prm_scale = 0.07216878364870322f;  // 1/sqrt(192)

    const float* in1    = (const float*)d_in[0];
    const float* in2    = (const float*)d_in[1];
    const float* W1     = (const float*)d_in[2];
    const float* b1     = (const float*)d_in[3];
    const float* W2     = (const float*)d_in[4];
    const float* b2     = (const float*)d_in[5];
    const float* kqv_w  = (const float*)d_in[6];
    const float* kqv_b  = (const float*)d_in[7];
    const float* proj_w = (const float*)d_in[8];
    const float* proj_b = (const float*)d_in[9];
    const float* ln1_g  = (const float*)d_in[10];
    const float* ln1_b  = (const float*)d_in[11];
    const float* ln2_g  = (const float*)d_in[12];
    const float* ln2_b  = (const float*)d_in[13];
    const float* mlp_w1 = (const float*)d_in[14];
    const float* mlp_b1 = (const float*)d_in[15];
    const float* mlp_w2 = (const float*)d_in[16];
    const float* mlp_b2 = (const float*)d_in[17];
    const float* w_prm  = (const float*)d_in[18];
    float* out = (float*)d_out;

    // ---- workspace layout ----
    char* p = (char*)d_ws;
    auto alloc = [&](long bytes)->char*{ char* r = p; p += (bytes + 255) & ~255L; return r; };

    // chunk-invariant bf16 weights
    u16* w1t   = (u16*)alloc(294912L * 2);   // [384][768]
    u16* w2t   = (u16*)alloc(147456L * 2);   // [384][384]
    u16* kqvt  = (u16*)alloc(442368L * 2);   // [1152][384]
    u16* prjt  = (u16*)alloc(147456L * 2);
    u16* m1t   = (u16*)alloc(147456L * 2);
    u16* m2t   = (u16*)alloc(147456L * 2);
    u16* wprmb = (u16*)alloc(256L * 384 * 2); // [256 pad][384], rows 192+ zeroed
    char* chunkBase = p;

    // per-batch ws bytes:
    // bf16: a0 768 + h1b 384 + xnb 384 + qpb 192 + kqvb 1152 + vT 384 + kpT 256 = 3520*T*2
    // f32 : xf 384 + xdv 1 + Dn 1 = 386*T*4
    // f32 : kpsum 192 + kptvA 7*73728 ; bf16 kptvb 73728
    const long perBatch = 3520L * T * 2 + 386L * T * 4
                        + (192L + 7L * 73728L) * 4 + 73728L * 2;
    const long fixed = (long)(chunkBase - (char*)d_ws) + (1L << 20);
    int nb = 2;
    for (int cand = 16; cand >= 2; cand >>= 1){
        if (fixed + (long)cand * perBatch + 128L * 1024 <= (long)ws_size){ nb = cand; break; }
    }

    const dim3 blk(256);

    // weight transpose/convert (idempotent per call)
    wt_kernel<<<dim3((294912 + 255) / 256), blk, 0, stream>>>(W1, w1t, 768, 384, 294912);
    wt_kernel<<<dim3((147456 + 255) / 256), blk, 0, stream>>>(W2, w2t, 384, 384, 147456);
    wt_kernel<<<dim3((442368 + 255) / 256), blk, 0, stream>>>(kqv_w, kqvt, 384, 1152, 442368);
    wt_kernel<<<dim3((147456 + 255) / 256), blk, 0, stream>>>(proj_w, prjt, 384, 384, 147456);
    wt_kernel<<<dim3((147456 + 255) / 256), blk, 0, stream>>>(mlp_w1, m1t, 384, 384, 147456);
    wt_kernel<<<dim3((147456 + 255) / 256), blk, 0, stream>>>(mlp_w2, m2t, 384, 384, 147456);
    zero_kernel<<<dim3(64), blk, 0, stream>>>((float*)wprmb, 256L * 384 / 2);
    cvt_kernel<<<dim3((18432 + 255) / 256), blk, 0, stream>>>(w_prm, wprmb, 18432);

    for (int b0 = 0; b0 < 16; b0 += nb){
        const long Mc = (long)nb * T;
        const int  gy128 = (int)(Mc / 128);
        const float* i1 = in1 + (long)b0 * T * 384;
        const float* i2 = in2 + (long)b0 * T * 384;
        float* outc = out + (long)b0 * T * 384;

        p = chunkBase;
        u16*  a0    = (u16*)alloc(Mc * 768 * 2);    // concat bf16 ; later mlp hidden
        u16*  h1b   = (u16*)alloc(Mc * 384 * 2);    // h1 bf16 ; later t_att bf16
        u16*  xnb   = (u16*)alloc(Mc * 384 * 2);    // xn bf16 ; later z bf16
        u16*  qpb   = (u16*)alloc(Mc * 192 * 2);    // qp bf16 (followed by allocs: OOB-read pad)
        u16*  kqvb  = (u16*)alloc(Mc * 1152 * 2);   // fused k|q|v bf16 [Mc][1152]
        u16*  vT    = (u16*)alloc(384L * Mc * 2);   // v transposed bf16 [384][Mc]
        u16*  kpT   = (u16*)alloc(256L * Mc * 2);   // kp transposed bf16 [256 pad][Mc]
        float* xf   = (float*)alloc(Mc * 384 * 4);  // x f32
        float* xdv  = (float*)alloc(Mc * 4);
        float* Dn   = (float*)alloc(Mc * 4);
        float* kpsum= (float*)alloc((long)nb * 192 * 4);
        float* kptvA= (float*)alloc((long)nb * 7 * 73728 * 4);  // split-K slices
        u16*  kptvb = (u16*)alloc((long)nb * 73728 * 2);
        (void)alloc(128L * 1024);                    // tail pad

        // 0) a0 = bf16(concat)
        {
            long nq = Mc * 192;
            ca_kernel<<<dim3((unsigned)((nq + 255) / 256)), blk, 0, stream>>>(i1, i2, a0, nq);
        }
        // 1) h1 = GELU(a0 @ W1t^T + b1)  [bf16]
        gemm_bf16<1,0,0><<<dim3(3, gy128, 1), blk, 0, stream>>>(
            a0, 768, w1t, 768, h1b, 384, b1, nullptr, nullptr, 0,
            (int)Mc, 384, 768, 1, 0,0,0,0, 0.f);
        // 2) x = h1 @ W2t^T + b2  [f32]
        gemm_bf16<2,0,0><<<dim3(3, gy128, 1), blk, 0, stream>>>(
            h1b, 384, w2t, 384, xf, 384, b2, nullptr, nullptr, 0,
            (int)Mc, 384, 384, 1, 0,0,0,0, 0.f);
        // 3) LN1 -> xn bf16
        ln_kernel<<<dim3((unsigned)(Mc / 4)), blk, 0, stream>>>(xf, nullptr, xnb, ln1_g, ln1_b);
        // 4) kqv = xn @ kqvt^T + kqv_b  [bf16, N=1152 fused]
        gemm_bf16<0,0,0><<<dim3(9, gy128, 1), blk, 0, stream>>>(
            xnb, 384, kqvt, 384, kqvb, 1152, kqv_b, nullptr, nullptr, 0,
            (int)Mc, 1152, 384, 1, 0,0,0,0, 0.f);
        // 5) xd_k ; kpT = exp(k @ wprm^T - xd)*scale  [bf16, transposed epilogue]
        xd_b_kernel<<<dim3((unsigned)(Mc / 4)), blk, 0, stream>>>(kqvb, 1152, xdv);
        gemm_bf16<7,0,1><<<dim3(2, gy128, 1), blk, 0, stream>>>(
            kqvb, 1152, wprmb, 384, kpT, (int)Mc, nullptr, xdv, nullptr, 0,
            (int)Mc, 192, 384, 1, 0,0,0,0, prm_scale);
        // 6) xd_q ; qp  [bf16 row-major]
        xd_b_kernel<<<dim3((unsigned)(Mc / 4)), blk, 0, stream>>>(kqvb + 384, 1152, xdv);
        gemm_bf16<6,0,1><<<dim3(2, gy128, 1), blk, 0, stream>>>(
            kqvb + 384, 1152, wprmb, 384, qpb, 192, nullptr, xdv, nullptr, 0,
            (int)Mc, 192, 384, 1, 0,0,0,0, prm_scale);
        // 7) kpsum from kpT rows (no atomics)
        kpsum2_kernel<<<dim3(nb * 48), blk, 0, stream>>>(kpT, kpsum, Mc, (int)T);
        // 8) vT = transpose of v (bf16, stride 1152)
        trb_kernel<<<dim3(6, (unsigned)(Mc / 64)), blk, 0, stream>>>(kqvb + 768, 1152, vT, Mc);
        // 9) kptv MFMA: [384][192] = vT(slice b) @ kpT(slice b)^T, split-K=7 slices
        gemm_bf16<8,0,1><<<dim3(2, 3, nb * 7), blk, 0, stream>>>(
            vT, (int)Mc, kpT, (int)Mc, kptvA, 192, nullptr, nullptr, nullptr, 0,
            384, 192, 3136, 7, 3136, 3136, 73728, 0, 0.f);
        kred_kernel<<<dim3((unsigned)((long)nb * 73728 / 256)), blk, 0, stream>>>(
            kptvA, kptvb, (long)nb * 73728);
        // 10) Dn
        dn_kernel<<<dim3((unsigned)(Mc / 4)), blk, 0, stream>>>(qpb, kpsum, Dn, (int)T);
        // 11) t_att = (qp @ kptv^T) / (Dn+1e-8)  [bf16, per-batch, row-guarded]
        gemm_bf16<3,1,0><<<dim3(3, 25, nb), blk, 0, stream>>>(
            qpb, 192, kptvb, 192, h1b, 384, nullptr, Dn, nullptr, 0,
            (int)T, 384, 192, 1, T*192, 73728, T*384, T, 0.f);
        // 12) y = t_att @ proj + proj_b + v(bf16)  -> outc (f32)
        gemm_bf16<9,0,0><<<dim3(3, gy128, 1), blk, 0, stream>>>(
            h1b, 384, prjt, 384, outc, 384, proj_b, nullptr, kqvb + 768, 1152,
            (int)Mc, 384, 384, 1, 0,0,0,0, 0.f);
        // 13) LN2 -> z bf16
        ln_kernel<<<dim3((unsigned)(Mc / 4)), blk, 0, stream>>>(outc, nullptr, xnb, ln2_g, ln2_b);
        // 14) h = GELU(z @ mlp1 + b)  [bf16] -> a0 region
        gemm_bf16<1,0,0><<<dim3(3, gy128, 1), blk, 0, stream>>>(
            xnb, 384, m1t, 384, a0, 384, mlp_b1, nullptr, nullptr, 0,
            (int)Mc, 384, 384, 1, 0,0,0,0, 0.f);
        // 15) out = h @ mlp2 + b + y  (in-place residual on outc)
        gemm_bf16<4,0,0><<<dim3(3, gy128, 1), blk, 0, stream>>>(
            a0, 384, m2t, 384, outc, 384, mlp_b2, nullptr, outc, 384,
            (int)Mc, 384, 384, 1, 0,0,0,0, 0.f);
    }
}

// Round 10
// 922.959 us; speedup vs baseline: 1.0932x; 1.0417x over previous
//
#include <hip/hip_runtime.h>
#include <math.h>

typedef unsigned short u16;
typedef unsigned int   u32;
typedef __attribute__((ext_vector_type(8))) short short8;
typedef __attribute__((ext_vector_type(4))) float f32x4;

typedef const void __attribute__((address_space(1))) gvoid_t;
typedef void       __attribute__((address_space(3))) svoid_t;

__device__ __forceinline__ void gload_lds16(const void* g, void* l){
    __builtin_amdgcn_global_load_lds((gvoid_t*)g, (svoid_t*)l, 16, 0, 0);
}

__device__ __forceinline__ float gelu_f(float x){
    return 0.5f * x * (1.0f + erff(x * 0.70710678118654752f));
}
__device__ __forceinline__ u16 f2b(float x){
    union{float f; u32 u;} v; v.f = x;
    u32 r = (v.u + 0x7fffu + ((v.u >> 16) & 1u)) >> 16;
    return (u16)r;
}
__device__ __forceinline__ float b2f(u16 h){
    union{u32 u; float f;} v; v.u = ((u32)h) << 16; return v.f;
}

// ===================== bf16 MFMA GEMM (frozen core; + T1 XCD swizzle) =====================
// A: bf16 [M][lda] row-major. B: bf16 [N][ldb] row-major. Tile 128x128, BK=64,
// 4 waves, XOR-swizzled LDS ([128][64], slot s of row m holds k8 = s^(m&7)),
// staged by global_load_lds(16B) with inverse swizzle folded into global addr.
// T1: within each z-slice, bijective XCD-chunked remap of the linear block id
// (m204 formula) so each XCD owns contiguous row-tiles incl. all col-tiles ->
// A-panel reuse hits the XCD-private L2 instead of re-fetching per column pass.
// EPI: 0:+bias->bf16  1:+bias,GELU->bf16  2:+bias->f32  3:/(rowv[r]+1e-8)->bf16
//      4:+bias+resid(f32,ldr)->f32  6:exp(acc-rowv[r])*scale->bf16
//      7:exp(acc-rowv[r])*scale->bf16 TRANSPOSED store C[col*ldc+row]
//      8:plain f32 store into per-splitK slice (C += bz*sC)
//      9:+bias+resid(bf16,ldr)->f32
template<int EPI, int GUARD, int CGUARD>
__global__ __launch_bounds__(256)
void gemm_bf16(const u16* __restrict__ A, int lda,
               const u16* __restrict__ B, int ldb,
               void* __restrict__ Cv, int ldc,
               const float* __restrict__ bias,
               const float* __restrict__ rowv,
               const void* __restrict__ resid, int ldr,
               int Mrows, int Ncols, int K, int splitK,
               long sA, long sB, long sC, long sRV,
               float scale)
{
    const int bz = blockIdx.z;
    const int b  = bz / splitK, kc = bz % splitK;
    A += (long)b * sA;  B += (long)b * sB;
    const float* rv = (EPI == 3 || EPI == 6 || EPI == 7) ? rowv + (long)b * sRV : nullptr;

    __shared__ u16 As0[8192];
    __shared__ u16 Bs0[8192];
    __shared__ u16 As1[8192];
    __shared__ u16 Bs1[8192];

    const int tid = threadIdx.x;

    // ---- T1 XCD-chunked bijective swizzle (within z-slice) ----
    const int gx  = gridDim.x;
    const int nwg = gx * gridDim.y;
    const int L   = blockIdx.y * gx + blockIdx.x;    // dispatch-linear (x fastest)
    const int q8  = nwg >> 3, r8 = nwg & 7;
    const int xc  = L & 7,   i8 = L >> 3;
    const int nid = (xc < r8 ? xc * (q8 + 1) : r8 * (q8 + 1) + (xc - r8) * q8) + i8;
    const int row0 = (nid / gx) * 128, col0 = (nid % gx) * 128;

    f32x4 acc[4][4] = {};

    const int l  = tid & 63, w4 = tid >> 6;
    const int wr = w4 >> 1, wc = w4 & 1;
    const int g  = l >> 4,  mr = l & 15;

    const int kLen   = K / splitK;
    const int kStart = kc * kLen;
    const int nt     = kLen / 64;

    const int m0   = w4 * 8 + (l >> 3);
    const int k8s  = (l & 7) ^ (m0 & 7);
    const int lBase = w4 * 512 + l * 8;
    const u16* gA0 = A + (long)(row0 + m0) * lda + kStart + k8s * 8;
    const u16* gB0 = B + (long)(col0 + m0) * ldb + kStart + k8s * 8;

    int aOff[4], bOff[4], sl[2];
    #pragma unroll
    for (int i = 0; i < 4; i++){
        aOff[i] = (wr * 64 + i * 16 + mr) * 64;
        bOff[i] = (wc * 64 + i * 16 + mr) * 64;
    }
    #pragma unroll
    for (int kk = 0; kk < 2; kk++)
        sl[kk] = (((kk * 4 + g) ^ (mr & 7)) & 7) * 8;

#define STAGE(AS, BS, KOFF)                                             \
    {                                                                   \
        _Pragma("unroll")                                               \
        for (int q = 0; q < 4; q++){                                    \
            gload_lds16(gA0 + (long)q * 32 * lda + (KOFF), &(AS)[lBase + q * 2048]); \
            gload_lds16(gB0 + (long)q * 32 * ldb + (KOFF), &(BS)[lBase + q * 2048]); \
        }                                                               \
    }

#define COMPUTE(AS, BS)                                                 \
    {                                                                   \
        short8 af[2][4], bfr[2][4];                                     \
        _Pragma("unroll")                                               \
        for (int kk = 0; kk < 2; kk++){                                 \
            _Pragma("unroll")                                           \
            for (int i = 0; i < 4; i++){                                \
                af[kk][i]  = *(const short8*)&(AS)[aOff[i] + sl[kk]];   \
                bfr[kk][i] = *(const short8*)&(BS)[bOff[i] + sl[kk]];   \
            }                                                           \
        }                                                               \
        _Pragma("unroll")                                               \
        for (int kk = 0; kk < 2; kk++)                                  \
            _Pragma("unroll")                                           \
            for (int i = 0; i < 4; i++)                                 \
                _Pragma("unroll")                                       \
                for (int j = 0; j < 4; j++)                             \
                    acc[i][j] = __builtin_amdgcn_mfma_f32_16x16x32_bf16(af[kk][i], bfr[kk][j], acc[i][j], 0, 0, 0); \
    }

    STAGE(As0, Bs0, 0);

    for (int t = 0; t < nt; ){
        __syncthreads();
        if (t + 1 < nt) STAGE(As1, Bs1, (t + 1) * 64);
        COMPUTE(As0, Bs0);
        t++;
        if (t >= nt) break;
        __syncthreads();
        if (t + 1 < nt) STAGE(As0, Bs0, (t + 1) * 64);
        COMPUTE(As1, Bs1);
        t++;
    }
#undef STAGE
#undef COMPUTE

    float* Cf = (float*)Cv + (EPI == 8 ? (long)bz : (long)b) * sC;
    u16*   Cb = (u16*)Cv   + (long)b * sC;

    #pragma unroll
    for (int i = 0; i < 4; i++){
        #pragma unroll
        for (int j = 0; j < 4; j++){
            const int col = col0 + wc * 64 + j * 16 + mr;
            if (CGUARD && col >= Ncols) continue;
            if (EPI == 7){
                const int rowb = row0 + wr * 64 + i * 16 + g * 4;
                u16 pk[4];
                #pragma unroll
                for (int r = 0; r < 4; r++)
                    pk[r] = f2b(expf(acc[i][j][r] - rv[rowb + r]) * scale);
                *(ushort4*)&Cb[(long)col * ldc + rowb] = *(ushort4*)pk;
            } else {
                float bv = 0.f;
                if (EPI == 0 || EPI == 1 || EPI == 2 || EPI == 4 || EPI == 9) bv = bias[col];
                #pragma unroll
                for (int r = 0; r < 4; r++){
                    const int row = row0 + wr * 64 + i * 16 + g * 4 + r;
                    if (GUARD && row >= Mrows) continue;
                    float vv = acc[i][j][r];
                    if      (EPI == 1){ vv += bv; vv = gelu_f(vv); }
                    else if (EPI == 3){ vv = vv / (rv[row] + 1e-8f); }
                    else if (EPI == 4){ vv += bv + ((const float*)resid)[(long)row * ldr + col]; }
                    else if (EPI == 6){ vv = expf(vv - rv[row]) * scale; }
                    else if (EPI == 8){ }
                    else if (EPI == 9){ vv += bv + b2f(((const u16*)resid)[(long)row * ldr + col]); }
                    else              { vv += bv; }
                    if (EPI == 2 || EPI == 4 || EPI == 8 || EPI == 9) Cf[(long)row * ldc + col] = vv;
                    else                                              Cb[(long)row * ldc + col] = f2b(vv);
                }
            }
        }
    }
}

// bf16 strided transpose: out[(cb+c)*R + rb+r] = in[(rb+r)*inStride + cb+c]
__global__ __launch_bounds__(256)
void trb_kernel(const u16* __restrict__ in, long inStride, u16* __restrict__ out, long R)
{
    __shared__ u16 t[64][72];
    const long cb = (long)blockIdx.x * 64, rb = (long)blockIdx.y * 64;
    const int tl = threadIdx.x & 63, tw = threadIdx.x >> 6;
    #pragma unroll
    for (int i = 0; i < 16; i++){
        const int r = tw + i * 4;
        t[r][tl] = in[(rb + r) * inStride + cb + tl];
    }
    __syncthreads();
    #pragma unroll
    for (int i = 0; i < 16; i++){
        const int c = tw + i * 4;
        out[(cb + c) * R + rb + tl] = t[tl][c];
    }
}

// kptvb[b][i] = bf16( sum_{kc<7} kptv_all[b*7+kc][i] )
__global__ __launch_bounds__(256)
void kred_kernel(const float* __restrict__ in, u16* __restrict__ out, long n)
{
    long idx = (long)blockIdx.x * 256 + threadIdx.x;
    if (idx >= n) return;
    const long b = idx / 73728, r = idx - b * 73728;
    const float* s = in + b * 7 * 73728L + r;
    float acc = 0.f;
    #pragma unroll
    for (int kc = 0; kc < 7; kc++) acc += s[kc * 73728L];
    out[idx] = f2b(acc);
}

// LayerNorm over D=384 (f32 in); optional f32 and bf16 outputs.
__global__ __launch_bounds__(256)
void ln_kernel(const float* __restrict__ x, float* __restrict__ of, u16* __restrict__ ob,
               const float* __restrict__ g, const float* __restrict__ bta)
{
    const int lane = threadIdx.x & 63;
    const long r = (long)blockIdx.x * 4 + (threadIdx.x >> 6);
    const float* xr = x + r * 384;
    float v[6]; float s = 0.f;
    #pragma unroll
    for (int i = 0; i < 6; i++){ v[i] = xr[lane + i*64]; s += v[i]; }
    #pragma unroll
    for (int off = 32; off; off >>= 1) s += __shfl_xor(s, off);
    const float mu = s * (1.0f/384.0f);
    float q = 0.f;
    #pragma unroll
    for (int i = 0; i < 6; i++){ float d = v[i] - mu; q += d*d; }
    #pragma unroll
    for (int off = 32; off; off >>= 1) q += __shfl_xor(q, off);
    const float inv = rsqrtf(q * (1.0f/384.0f) + 1e-5f);
    #pragma unroll
    for (int i = 0; i < 6; i++){
        const int c = lane + i*64;
        const float val = (v[i] - mu) * inv * g[c] + bta[c];
        if (of) of[r * 384 + c] = val;
        if (ob) ob[r * 384 + c] = f2b(val);
    }
}

// xd[r] = 0.5*||x_row||^2 over 384 bf16 cols, row stride `stride`
__global__ __launch_bounds__(256)
void xd_b_kernel(const u16* __restrict__ x, long stride, float* __restrict__ xd)
{
    const int lane = threadIdx.x & 63;
    const long r = (long)blockIdx.x * 4 + (threadIdx.x >> 6);
    const u16* xr = x + r * stride;
    float s = 0.f;
    #pragma unroll
    for (int i = 0; i < 6; i++){ float a = b2f(xr[lane + i*64]); s += a*a; }
    #pragma unroll
    for (int off = 32; off; off >>= 1) s += __shfl_xor(s, off);
    if (lane == 0) xd[r] = 0.5f * s;
}

// Dn[r] = dot(qp_bf16[r,:192], kpsum[r/T,:192])
__global__ __launch_bounds__(256)
void dn_kernel(const u16* __restrict__ qp, const float* __restrict__ kpsum,
               float* __restrict__ Dn, int T)
{
    const int lane = threadIdx.x & 63;
    const long r = (long)blockIdx.x * 4 + (threadIdx.x >> 6);
    const int b = (int)(r / T);
    const u16* qr = qp + r * 192;
    const float* ks = kpsum + (long)b * 192;
    float s = 0.f;
    #pragma unroll
    for (int i = 0; i < 3; i++){ const int m = lane + i*64; s += b2f(qr[m]) * ks[m]; }
    #pragma unroll
    for (int off = 32; off; off >>= 1) s += __shfl_xor(s, off);
    if (lane == 0) Dn[r] = s;
}

// kpsum[bl][m] = sum_t kpT[m][bl*T + t]   (one wave per (m,bl); no atomics)
__global__ __launch_bounds__(256)
void kpsum2_kernel(const u16* __restrict__ kpT, float* __restrict__ kpsum, long Mc, int T)
{
    const int lane = threadIdx.x & 63;
    const int gw = blockIdx.x * 4 + (threadIdx.x >> 6);
    const int m = gw % 192, bl = gw / 192;
    const u16* row = kpT + (long)m * Mc + (long)bl * T;
    float s = 0.f;
    for (int i = lane; i < T; i += 64) s += b2f(row[i]);
    #pragma unroll
    for (int off = 32; off; off >>= 1) s += __shfl_xor(s, off);
    if (lane == 0) kpsum[bl * 192 + m] = s;
}

__global__ __launch_bounds__(256)
void zero_kernel(float* __restrict__ p, long n)
{
    long i = (long)blockIdx.x * 256 + threadIdx.x;
    long stride = (long)gridDim.x * 256;
    for (; i < n; i += stride) p[i] = 0.f;
}

// concat(in1,in2) row-major -> bf16 [Mc][768]
__global__ __launch_bounds__(256)
void ca_kernel(const float* __restrict__ i1, const float* __restrict__ i2,
               u16* __restrict__ a0, long nquad)
{
    long idx = (long)blockIdx.x * 256 + threadIdx.x;
    if (idx >= nquad) return;
    const long r = idx / 192;
    const int  c0 = (int)(idx % 192) * 4;
    const float* src = (c0 < 384) ? &i1[r * 384 + c0] : &i2[r * 384 + (c0 - 384)];
    float4 v = *(const float4*)src;
    u32 w0 = (u32)f2b(v.x) | ((u32)f2b(v.y) << 16);
    u32 w1 = (u32)f2b(v.z) | ((u32)f2b(v.w) << 16);
    *(uint2*)&a0[r * 768 + c0] = make_uint2(w0, w1);
}

// wt[n*K + k] = bf16(w[k*N + n])
__global__ __launch_bounds__(256)
void wt_kernel(const float* __restrict__ w, u16* __restrict__ wt, int K, int N, long total)
{
    long idx = (long)blockIdx.x * 256 + threadIdx.x;
    if (idx >= total) return;
    const long n = idx / K, k = idx - n * K;
    wt[idx] = f2b(w[k * N + n]);
}

// flat f32 -> bf16
__global__ __launch_bounds__(256)
void cvt_kernel(const float* __restrict__ s, u16* __restrict__ d, long n4)
{
    long idx = (long)blockIdx.x * 256 + threadIdx.x;
    if (idx >= n4) return;
    float4 v = *(const float4*)&s[idx * 4];
    u32 w0 = (u32)f2b(v.x) | ((u32)f2b(v.y) << 16);
    u32 w1 = (u32)f2b(v.z) | ((u32)f2b(v.w) << 16);
    *(uint2*)&d[idx * 4] = make_uint2(w0, w1);
}

extern "C" void kernel_launch(void* const* d_in, const int* in_sizes, int n_in,
                              void* d_out, int out_size, void* d_ws, size_t ws_size,
                              hipStream_t stream)
{
    const long T = 3136;
    const float prm_scale = 0.07216878364870322f;  // 1/sqrt(192)

    const float* in1    = (const float*)d_in[0];
    const float* in2    = (const float*)d_in[1];
    const float* W1     = (const float*)d_in[2];
    const float* b1     = (const float*)d_in[3];
    const float* W2     = (const float*)d_in[4];
    const float* b2     = (const float*)d_in[5];
    const float* kqv_w  = (const float*)d_in[6];
    const float* kqv_b  = (const float*)d_in[7];
    const float* proj_w = (const float*)d_in[8];
    const float* proj_b = (const float*)d_in[9];
    const float* ln1_g  = (const float*)d_in[10];
    const float* ln1_b  = (const float*)d_in[11];
    const float* ln2_g  = (const float*)d_in[12];
    const float* ln2_b  = (const float*)d_in[13];
    const float* mlp_w1 = (const float*)d_in[14];
    const float* mlp_b1 = (const float*)d_in[15];
    const float* mlp_w2 = (const float*)d_in[16];
    const float* mlp_b2 = (const float*)d_in[17];
    const float* w_prm  = (const float*)d_in[18];
    float* out = (float*)d_out;

    // ---- workspace layout ----
    char* p = (char*)d_ws;
    auto alloc = [&](long bytes)->char*{ char* r = p; p += (bytes + 255) & ~255L; return r; };

    // chunk-invariant bf16 weights
    u16* w1t   = (u16*)alloc(294912L * 2);   // [384][768]
    u16* w2t   = (u16*)alloc(147456L * 2);   // [384][384]
    u16* kqvt  = (u16*)alloc(442368L * 2);   // [1152][384]
    u16* prjt  = (u16*)alloc(147456L * 2);
    u16* m1t   = (u16*)alloc(147456L * 2);
    u16* m2t   = (u16*)alloc(147456L * 2);
    u16* wprmb = (u16*)alloc(256L * 384 * 2); // [256 pad][384], rows 192+ zeroed
    char* chunkBase = p;

    // per-batch ws bytes:
    // bf16: a0 768 + h1b 384 + xnb 384 + qpb 192 + kqvb 1152 + vT 384 + kpT 256 = 3520*T*2
    // f32 : xf 384 + xdv 1 + Dn 1 = 386*T*4
    // f32 : kpsum 192 + kptvA 7*73728 ; bf16 kptvb 73728
    const long perBatch = 3520L * T * 2 + 386L * T * 4
                        + (192L + 7L * 73728L) * 4 + 73728L * 2;
    const long fixed = (long)(chunkBase - (char*)d_ws) + (1L << 20);
    int nb = 2;
    for (int cand = 16; cand >= 2; cand >>= 1){
        if (fixed + (long)cand * perBatch + 128L * 1024 <= (long)ws_size){ nb = cand; break; }
    }

    const dim3 blk(256);

    // weight transpose/convert (idempotent per call)
    wt_kernel<<<dim3((294912 + 255) / 256), blk, 0, stream>>>(W1, w1t, 768, 384, 294912);
    wt_kernel<<<dim3((147456 + 255) / 256), blk, 0, stream>>>(W2, w2t, 384, 384, 147456);
    wt_kernel<<<dim3((442368 + 255) / 256), blk, 0, stream>>>(kqv_w, kqvt, 384, 1152, 442368);
    wt_kernel<<<dim3((147456 + 255) / 256), blk, 0, stream>>>(proj_w, prjt, 384, 384, 147456);
    wt_kernel<<<dim3((147456 + 255) / 256), blk, 0, stream>>>(mlp_w1, m1t, 384, 384, 147456);
    wt_kernel<<<dim3((147456 + 255) / 256), blk, 0, stream>>>(mlp_w2, m2t, 384, 384, 147456);
    zero_kernel<<<dim3(64), blk, 0, stream>>>((float*)wprmb, 256L * 384 / 2);
    cvt_kernel<<<dim3((18432 + 255) / 256), blk, 0, stream>>>(w_prm, wprmb, 18432);

    for (int b0 = 0; b0 < 16; b0 += nb){
        const long Mc = (long)nb * T;
        const int  gy128 = (int)(Mc / 128);
        const float* i1 = in1 + (long)b0 * T * 384;
        const float* i2 = in2 + (long)b0 * T * 384;
        float* outc = out + (long)b0 * T * 384;

        p = chunkBase;
        u16*  a0    = (u16*)alloc(Mc * 768 * 2);    // concat bf16 ; later mlp hidden
        u16*  h1b   = (u16*)alloc(Mc * 384 * 2);    // h1 bf16 ; later t_att bf16
        u16*  xnb   = (u16*)alloc(Mc * 384 * 2);    // xn bf16 ; later z bf16
        u16*  qpb   = (u16*)alloc(Mc * 192 * 2);    // qp bf16 (followed by allocs: OOB-read pad)
        u16*  kqvb  = (u16*)alloc(Mc * 1152 * 2);   // fused k|q|v bf16 [Mc][1152]
        u16*  vT    = (u16*)alloc(384L * Mc * 2);   // v transposed bf16 [384][Mc]
        u16*  kpT   = (u16*)alloc(256L * Mc * 2);   // kp transposed bf16 [256 pad][Mc]
        float* xf   = (float*)alloc(Mc * 384 * 4);  // x f32
        float* xdv  = (float*)alloc(Mc * 4);
        float* Dn   = (float*)alloc(Mc * 4);
        float* kpsum= (float*)alloc((long)nb * 192 * 4);
        float* kptvA= (float*)alloc((long)nb * 7 * 73728 * 4);  // split-K slices
        u16*  kptvb = (u16*)alloc((long)nb * 73728 * 2);
        (void)alloc(128L * 1024);                    // tail pad

        // 0) a0 = bf16(concat)
        {
            long nq = Mc * 192;
            ca_kernel<<<dim3((unsigned)((nq + 255) / 256)), blk, 0, stream>>>(i1, i2, a0, nq);
        }
        // 1) h1 = GELU(a0 @ W1t^T + b1)  [bf16]
        gemm_bf16<1,0,0><<<dim3(3, gy128, 1), blk, 0, stream>>>(
            a0, 768, w1t, 768, h1b, 384, b1, nullptr, nullptr, 0,
            (int)Mc, 384, 768, 1, 0,0,0,0, 0.f);
        // 2) x = h1 @ W2t^T + b2  [f32]
        gemm_bf16<2,0,0><<<dim3(3, gy128, 1), blk, 0, stream>>>(
            h1b, 384, w2t, 384, xf, 384, b2, nullptr, nullptr, 0,
            (int)Mc, 384, 384, 1, 0,0,0,0, 0.f);
        // 3) LN1 -> xn bf16
        ln_kernel<<<dim3((unsigned)(Mc / 4)), blk, 0, stream>>>(xf, nullptr, xnb, ln1_g, ln1_b);
        // 4) kqv = xn @ kqvt^T + kqv_b  [bf16, N=1152 fused]
        gemm_bf16<0,0,0><<<dim3(9, gy128, 1), blk, 0, stream>>>(
            xnb, 384, kqvt, 384, kqvb, 1152, kqv_b, nullptr, nullptr, 0,
            (int)Mc, 1152, 384, 1, 0,0,0,0, 0.f);
        // 5) xd_k ; kpT = exp(k @ wprm^T - xd)*scale  [bf16, transposed epilogue]
        xd_b_kernel<<<dim3((unsigned)(Mc / 4)), blk, 0, stream>>>(kqvb, 1152, xdv);
        gemm_bf16<7,0,1><<<dim3(2, gy128, 1), blk, 0, stream>>>(
            kqvb, 1152, wprmb, 384, kpT, (int)Mc, nullptr, xdv, nullptr, 0,
            (int)Mc, 192, 384, 1, 0,0,0,0, prm_scale);
        // 6) xd_q ; qp  [bf16 row-major]
        xd_b_kernel<<<dim3((unsigned)(Mc / 4)), blk, 0, stream>>>(kqvb + 384, 1152, xdv);
        gemm_bf16<6,0,1><<<dim3(2, gy128, 1), blk, 0, stream>>>(
            kqvb + 384, 1152, wprmb, 384, qpb, 192, nullptr, xdv, nullptr, 0,
            (int)Mc, 192, 384, 1, 0,0,0,0, prm_scale);
        // 7) kpsum from kpT rows (no atomics)
        kpsum2_kernel<<<dim3(nb * 48), blk, 0, stream>>>(kpT, kpsum, Mc, (int)T);
        // 8) vT = transpose of v (bf16, stride 1152)
        trb_kernel<<<dim3(6, (unsigned)(Mc / 64)), blk, 0, stream>>>(kqvb + 768, 1152, vT, Mc);
        // 9) kptv MFMA: [384][192] = vT(slice b) @ kpT(slice b)^T, split-K=7 slices
        gemm_bf16<8,0,1><<<dim3(2, 3, nb * 7), blk, 0, stream>>>(
            vT, (int)Mc, kpT, (int)Mc, kptvA, 192, nullptr, nullptr, nullptr, 0,
            384, 192, 3136, 7, 3136, 3136, 73728, 0, 0.f);
        kred_kernel<<<dim3((unsigned)((long)nb * 73728 / 256)), blk, 0, stream>>>(
            kptvA, kptvb, (long)nb * 73728);
        // 10) Dn
        dn_kernel<<<dim3((unsigned)(Mc / 4)), blk, 0, stream>>>(qpb, kpsum, Dn, (int)T);
        // 11) t_att = (qp @ kptv^T) / (Dn+1e-8)  [bf16, per-batch, row-guarded]
        gemm_bf16<3,1,0><<<dim3(3, 25, nb), blk, 0, stream>>>(
            qpb, 192, kptvb, 192, h1b, 384, nullptr, Dn, nullptr, 0,
            (int)T, 384, 192, 1, T*192, 73728, T*384, T, 0.f);
        // 12) y = t_att @ proj + proj_b + v(bf16)  -> outc (f32)
        gemm_bf16<9,0,0><<<dim3(3, gy128, 1), blk, 0, stream>>>(
            h1b, 384, prjt, 384, outc, 384, proj_b, nullptr, kqvb + 768, 1152,
            (int)Mc, 384, 384, 1, 0,0,0,0, 0.f);
        // 13) LN2 -> z bf16
        ln_kernel<<<dim3((unsigned)(Mc / 4)), blk, 0, stream>>>(outc, nullptr, xnb, ln2_g, ln2_b);
        // 14) h = GELU(z @ mlp1 + b)  [bf16] -> a0 region
        gemm_bf16<1,0,0><<<dim3(3, gy128, 1), blk, 0, stream>>>(
            xnb, 384, m1t, 384, a0, 384, mlp_b1, nullptr, nullptr, 0,
            (int)Mc, 384, 384, 1, 0,0,0,0, 0.f);
        // 15) out = h @ mlp2 + b + y  (in-place residual on outc)
        gemm_bf16<4,0,0><<<dim3(3, gy128, 1), blk, 0, stream>>>(
            a0, 384, m2t, 384, outc, 384, mlp_b2, nullptr, outc, 384,
            (int)Mc, 384, 384, 1, 0,0,0,0, 0.f);
    }
}

// Round 11
// 875.513 us; speedup vs baseline: 1.1525x; 1.0542x over previous
//
#include <hip/hip_runtime.h>
#include <math.h>

typedef unsigned short u16;
typedef unsigned int   u32;
typedef __attribute__((ext_vector_type(8))) short short8;
typedef __attribute__((ext_vector_type(4))) float f32x4;

typedef const void __attribute__((address_space(1))) gvoid_t;
typedef void       __attribute__((address_space(3))) svoid_t;

__device__ __forceinline__ void gload_lds16(const void* g, void* l){
    __builtin_amdgcn_global_load_lds((gvoid_t*)g, (svoid_t*)l, 16, 0, 0);
}

__device__ __forceinline__ float gelu_f(float x){
    return 0.5f * x * (1.0f + erff(x * 0.70710678118654752f));
}
__device__ __forceinline__ u16 f2b(float x){
    union{float f; u32 u;} v; v.f = x;
    u32 r = (v.u + 0x7fffu + ((v.u >> 16) & 1u)) >> 16;
    return (u16)r;
}
__device__ __forceinline__ float b2f(u16 h){
    union{u32 u; float f;} v; v.u = ((u32)h) << 16; return v.f;
}

// ===================== bf16 MFMA GEMM (frozen core; T1 swizzle; in-GEMM xd) ===========
// A: bf16 [M][lda] row-major. B: bf16 [N][ldb] row-major. Tile 128x128, BK=64,
// 4 waves, XOR-swizzled LDS, global_load_lds staging w/ inverse swizzle on src.
// EPI: 0:+bias->bf16  1:+bias,GELU->bf16  3:/(rowv[r]+1e-8)->bf16
//      4:+bias+resid(f32,ldr)->f32  8:plain f32 store into per-splitK slice
//      9:+bias+resid(bf16,ldr)->f32
//      10:FAVOR dual (in-GEMM xd): acc Sum(a^2) during COMPUTE; out =
//         exp(acc - 0.5*||a_row||^2)*scale -> bf16; z==0: TRANSPOSED store to
//         Cv[col*ldc+row] (kpT); z==1: row store to resid[row*ldr+col] (qp).
//         A += z*sA selects k vs q slice.
template<int EPI, int GUARD, int CGUARD>
__global__ __launch_bounds__(256)
void gemm_bf16(const u16* __restrict__ A, int lda,
               const u16* __restrict__ B, int ldb,
               void* __restrict__ Cv, int ldc,
               const float* __restrict__ bias,
               const float* __restrict__ rowv,
               void* __restrict__ resid, int ldr,
               int Mrows, int Ncols, int K, int splitK,
               long sA, long sB, long sC, long sRV,
               float scale)
{
    const int bz = blockIdx.z;
    const int b  = bz / splitK, kc = bz % splitK;
    A += (long)b * sA;  B += (long)b * sB;
    const float* rv = (EPI == 3) ? rowv + (long)b * sRV : nullptr;

    __shared__ u16 As0[8192];
    __shared__ u16 Bs0[8192];
    __shared__ u16 As1[8192];
    __shared__ u16 Bs1[8192];
    __shared__ float xds[128];   // EPI10: per-row 0.5*||a||^2

    const int tid = threadIdx.x;

    // T1 XCD-chunked bijective swizzle (within z-slice)
    const int gx  = gridDim.x;
    const int nwg = gx * gridDim.y;
    const int L   = blockIdx.y * gx + blockIdx.x;
    const int q8  = nwg >> 3, r8 = nwg & 7;
    const int xc  = L & 7,   i8 = L >> 3;
    const int nid = (xc < r8 ? xc * (q8 + 1) : r8 * (q8 + 1) + (xc - r8) * q8) + i8;
    const int row0 = (nid / gx) * 128, col0 = (nid % gx) * 128;

    f32x4 acc[4][4] = {};
    float sqacc[4] = {0.f, 0.f, 0.f, 0.f};

    const int l  = tid & 63, w4 = tid >> 6;
    const int wr = w4 >> 1, wc = w4 & 1;
    const int g  = l >> 4,  mr = l & 15;

    const int kLen   = K / splitK;
    const int kStart = kc * kLen;
    const int nt     = kLen / 64;

    const int m0   = w4 * 8 + (l >> 3);
    const int k8s  = (l & 7) ^ (m0 & 7);
    const int lBase = w4 * 512 + l * 8;
    const u16* gA0 = A + (long)(row0 + m0) * lda + kStart + k8s * 8;
    const u16* gB0 = B + (long)(col0 + m0) * ldb + kStart + k8s * 8;

    int aOff[4], bOff[4], sl[2];
    #pragma unroll
    for (int i = 0; i < 4; i++){
        aOff[i] = (wr * 64 + i * 16 + mr) * 64;
        bOff[i] = (wc * 64 + i * 16 + mr) * 64;
    }
    #pragma unroll
    for (int kk = 0; kk < 2; kk++)
        sl[kk] = (((kk * 4 + g) ^ (mr & 7)) & 7) * 8;

#define STAGE(AS, BS, KOFF)                                             \
    {                                                                   \
        _Pragma("unroll")                                               \
        for (int q = 0; q < 4; q++){                                    \
            gload_lds16(gA0 + (long)q * 32 * lda + (KOFF), &(AS)[lBase + q * 2048]); \
            gload_lds16(gB0 + (long)q * 32 * ldb + (KOFF), &(BS)[lBase + q * 2048]); \
        }                                                               \
    }

#define COMPUTE(AS, BS)                                                 \
    {                                                                   \
        short8 af[2][4], bfr[2][4];                                     \
        _Pragma("unroll")                                               \
        for (int kk = 0; kk < 2; kk++){                                 \
            _Pragma("unroll")                                           \
            for (int i = 0; i < 4; i++){                                \
                af[kk][i]  = *(const short8*)&(AS)[aOff[i] + sl[kk]];   \
                bfr[kk][i] = *(const short8*)&(BS)[bOff[i] + sl[kk]];   \
            }                                                           \
        }                                                               \
        if (EPI == 10){                                                 \
            _Pragma("unroll")                                           \
            for (int kk = 0; kk < 2; kk++)                              \
                _Pragma("unroll")                                       \
                for (int i = 0; i < 4; i++)                             \
                    _Pragma("unroll")                                   \
                    for (int e = 0; e < 8; e++){                        \
                        float f_ = b2f((u16)af[kk][i][e]);              \
                        sqacc[i] += f_ * f_;                            \
                    }                                                   \
        }                                                               \
        _Pragma("unroll")                                               \
        for (int kk = 0; kk < 2; kk++)                                  \
            _Pragma("unroll")                                           \
            for (int i = 0; i < 4; i++)                                 \
                _Pragma("unroll")                                       \
                for (int j = 0; j < 4; j++)                             \
                    acc[i][j] = __builtin_amdgcn_mfma_f32_16x16x32_bf16(af[kk][i], bfr[kk][j], acc[i][j], 0, 0, 0); \
    }

    STAGE(As0, Bs0, 0);

    for (int t = 0; t < nt; ){
        __syncthreads();
        if (t + 1 < nt) STAGE(As1, Bs1, (t + 1) * 64);
        COMPUTE(As0, Bs0);
        t++;
        if (t >= nt) break;
        __syncthreads();
        if (t + 1 < nt) STAGE(As0, Bs0, (t + 1) * 64);
        COMPUTE(As1, Bs1);
        t++;
    }
#undef STAGE
#undef COMPUTE

    if (EPI == 10){
        // reduce Sum(a^2) across the 4 g-lane groups (lanes differ in bits 4,5)
        #pragma unroll
        for (int i = 0; i < 4; i++){
            float s = sqacc[i];
            s += __shfl_xor(s, 16);
            s += __shfl_xor(s, 32);
            if (l < 16) xds[wr * 64 + i * 16 + l] = 0.5f * s;
        }
        __syncthreads();
    }

    float* Cf = (float*)Cv + (EPI == 8 ? (long)bz : (long)b) * sC;
    u16*   Cb = (u16*)Cv   + (EPI == 10 ? 0L : (long)b * sC);

    #pragma unroll
    for (int i = 0; i < 4; i++){
        #pragma unroll
        for (int j = 0; j < 4; j++){
            const int col = col0 + wc * 64 + j * 16 + mr;
            if (CGUARD && col >= Ncols) continue;
            if (EPI == 10){
                const int lrow = wr * 64 + i * 16 + g * 4;
                if (bz == 0){
                    u16 pk[4];
                    #pragma unroll
                    for (int r = 0; r < 4; r++)
                        pk[r] = f2b(expf(acc[i][j][r] - xds[lrow + r]) * scale);
                    *(ushort4*)&Cb[(long)col * ldc + row0 + lrow] = *(ushort4*)pk;
                } else {
                    u16* qo = (u16*)resid;
                    #pragma unroll
                    for (int r = 0; r < 4; r++)
                        qo[(long)(row0 + lrow + r) * ldr + col] =
                            f2b(expf(acc[i][j][r] - xds[lrow + r]) * scale);
                }
            } else {
                float bv = 0.f;
                if (EPI == 0 || EPI == 1 || EPI == 4 || EPI == 9) bv = bias[col];
                #pragma unroll
                for (int r = 0; r < 4; r++){
                    const int row = row0 + wr * 64 + i * 16 + g * 4 + r;
                    if (GUARD && row >= Mrows) continue;
                    float vv = acc[i][j][r];
                    if      (EPI == 1){ vv += bv; vv = gelu_f(vv); }
                    else if (EPI == 3){ vv = vv / (rv[row] + 1e-8f); }
                    else if (EPI == 4){ vv += bv + ((const float*)resid)[(long)row * ldr + col]; }
                    else if (EPI == 8){ }
                    else if (EPI == 9){ vv += bv + b2f(((const u16*)resid)[(long)row * ldr + col]); }
                    else              { vv += bv; }
                    if (EPI == 4 || EPI == 8 || EPI == 9) Cf[(long)row * ldc + col] = vv;
                    else                                  Cb[(long)row * ldc + col] = f2b(vv);
                }
            }
        }
    }
}

// bf16 strided transpose: out[(cb+c)*R + rb+r] = in[(rb+r)*inStride + cb+c]
__global__ __launch_bounds__(256)
void trb_kernel(const u16* __restrict__ in, long inStride, u16* __restrict__ out, long R)
{
    __shared__ u16 t[64][72];
    const long cb = (long)blockIdx.x * 64, rb = (long)blockIdx.y * 64;
    const int tl = threadIdx.x & 63, tw = threadIdx.x >> 6;
    #pragma unroll
    for (int i = 0; i < 16; i++){
        const int r = tw + i * 4;
        t[r][tl] = in[(rb + r) * inStride + cb + tl];
    }
    __syncthreads();
    #pragma unroll
    for (int i = 0; i < 16; i++){
        const int c = tw + i * 4;
        out[(cb + c) * R + rb + tl] = t[tl][c];
    }
}

__global__ __launch_bounds__(256)
void kred_kernel(const float* __restrict__ in, u16* __restrict__ out, long n)
{
    long idx = (long)blockIdx.x * 256 + threadIdx.x;
    if (idx >= n) return;
    const long b = idx / 73728, r = idx - b * 73728;
    const float* s = in + b * 7 * 73728L + r;
    float acc = 0.f;
    #pragma unroll
    for (int kc = 0; kc < 7; kc++) acc += s[kc * 73728L];
    out[idx] = f2b(acc);
}

// LayerNorm over D=384; input f32 (INF32=1) or bf16 (INF32=0); bf16 out.
template<int INF32>
__global__ __launch_bounds__(256)
void ln_kernel(const void* __restrict__ xv, u16* __restrict__ ob,
               const float* __restrict__ g, const float* __restrict__ bta)
{
    const int lane = threadIdx.x & 63;
    const long r = (long)blockIdx.x * 4 + (threadIdx.x >> 6);
    float v[6]; float s = 0.f;
    #pragma unroll
    for (int i = 0; i < 6; i++){
        const int c = lane + i * 64;
        v[i] = INF32 ? ((const float*)xv)[r * 384 + c]
                     : b2f(((const u16*)xv)[r * 384 + c]);
        s += v[i];
    }
    #pragma unroll
    for (int off = 32; off; off >>= 1) s += __shfl_xor(s, off);
    const float mu = s * (1.0f/384.0f);
    float q = 0.f;
    #pragma unroll
    for (int i = 0; i < 6; i++){ float d = v[i] - mu; q += d*d; }
    #pragma unroll
    for (int off = 32; off; off >>= 1) q += __shfl_xor(q, off);
    const float inv = rsqrtf(q * (1.0f/384.0f) + 1e-5f);
    #pragma unroll
    for (int i = 0; i < 6; i++){
        const int c = lane + i*64;
        ob[r * 384 + c] = f2b((v[i] - mu) * inv * g[c] + bta[c]);
    }
}

// Dn[r] = dot(qp_bf16[r,:192], kpsum[r/T,:192])
__global__ __launch_bounds__(256)
void dn_kernel(const u16* __restrict__ qp, const float* __restrict__ kpsum,
               float* __restrict__ Dn, int T)
{
    const int lane = threadIdx.x & 63;
    const long r = (long)blockIdx.x * 4 + (threadIdx.x >> 6);
    const int b = (int)(r / T);
    const u16* qr = qp + r * 192;
    const float* ks = kpsum + (long)b * 192;
    float s = 0.f;
    #pragma unroll
    for (int i = 0; i < 3; i++){ const int m = lane + i*64; s += b2f(qr[m]) * ks[m]; }
    #pragma unroll
    for (int off = 32; off; off >>= 1) s += __shfl_xor(s, off);
    if (lane == 0) Dn[r] = s;
}

// kpsum[bl][m] = sum_t kpT[m][bl*T + t]
__global__ __launch_bounds__(256)
void kpsum2_kernel(const u16* __restrict__ kpT, float* __restrict__ kpsum, long Mc, int T)
{
    const int lane = threadIdx.x & 63;
    const int gw = blockIdx.x * 4 + (threadIdx.x >> 6);
    const int m = gw % 192, bl = gw / 192;
    const u16* row = kpT + (long)m * Mc + (long)bl * T;
    float s = 0.f;
    for (int i = lane; i < T; i += 64) s += b2f(row[i]);
    #pragma unroll
    for (int off = 32; off; off >>= 1) s += __shfl_xor(s, off);
    if (lane == 0) kpsum[bl * 192 + m] = s;
}

__global__ __launch_bounds__(256)
void zero_kernel(float* __restrict__ p, long n)
{
    long i = (long)blockIdx.x * 256 + threadIdx.x;
    long stride = (long)gridDim.x * 256;
    for (; i < n; i += stride) p[i] = 0.f;
}

// concat(in1,in2) row-major -> bf16 [Mc][768]
__global__ __launch_bounds__(256)
void ca_kernel(const float* __restrict__ i1, const float* __restrict__ i2,
               u16* __restrict__ a0, long nquad)
{
    long idx = (long)blockIdx.x * 256 + threadIdx.x;
    if (idx >= nquad) return;
    const long r = idx / 192;
    const int  c0 = (int)(idx % 192) * 4;
    const float* src = (c0 < 384) ? &i1[r * 384 + c0] : &i2[r * 384 + (c0 - 384)];
    float4 v = *(const float4*)src;
    u32 w0 = (u32)f2b(v.x) | ((u32)f2b(v.y) << 16);
    u32 w1 = (u32)f2b(v.z) | ((u32)f2b(v.w) << 16);
    *(uint2*)&a0[r * 768 + c0] = make_uint2(w0, w1);
}

// wt[n*K + k] = bf16(w[k*N + n])
__global__ __launch_bounds__(256)
void wt_kernel(const float* __restrict__ w, u16* __restrict__ wt, int K, int N, long total)
{
    long idx = (long)blockIdx.x * 256 + threadIdx.x;
    if (idx >= total) return;
    const long n = idx / K, k = idx - n * K;
    wt[idx] = f2b(w[k * N + n]);
}

// flat f32 -> bf16
__global__ __launch_bounds__(256)
void cvt_kernel(const float* __restrict__ s, u16* __restrict__ d, long n4)
{
    long idx = (long)blockIdx.x * 256 + threadIdx.x;
    if (idx >= n4) return;
    float4 v = *(const float4*)&s[idx * 4];
    u32 w0 = (u32)f2b(v.x) | ((u32)f2b(v.y) << 16);
    u32 w1 = (u32)f2b(v.z) | ((u32)f2b(v.w) << 16);
    *(uint2*)&d[idx * 4] = make_uint2(w0, w1);
}

extern "C" void kernel_launch(void* const* d_in, const int* in_sizes, int n_in,
                              void* d_out, int out_size, void* d_ws, size_t ws_size,
                              hipStream_t stream)
{
    const long T = 3136;
    const float prm_scale = 0.07216878364870322f;  // 1/sqrt(192)

    const float* in1    = (const float*)d_in[0];
    const float* in2    = (const float*)d_in[1];
    const float* W1     = (const float*)d_in[2];
    const float* b1     = (const float*)d_in[3];
    const float* W2     = (const float*)d_in[4];
    const float* b2     = (const float*)d_in[5];
    const float* kqv_w  = (const float*)d_in[6];
    const float* kqv_b  = (const float*)d_in[7];
    const float* proj_w = (const float*)d_in[8];
    const float* proj_b = (const float*)d_in[9];
    const float* ln1_g  = (const float*)d_in[10];
    const float* ln1_b  = (const float*)d_in[11];
    const float* ln2_g  = (const float*)d_in[12];
    const float* ln2_b  = (const float*)d_in[13];
    const float* mlp_w1 = (const float*)d_in[14];
    const float* mlp_b1 = (const float*)d_in[15];
    const float* mlp_w2 = (const float*)d_in[16];
    const float* mlp_b2 = (const float*)d_in[17];
    const float* w_prm  = (const float*)d_in[18];
    float* out = (float*)d_out;

    char* p = (char*)d_ws;
    auto alloc = [&](long bytes)->char*{ char* r = p; p += (bytes + 255) & ~255L; return r; };

    // chunk-invariant bf16 weights
    u16* w1t   = (u16*)alloc(294912L * 2);
    u16* w2t   = (u16*)alloc(147456L * 2);
    u16* kqvt  = (u16*)alloc(442368L * 2);
    u16* prjt  = (u16*)alloc(147456L * 2);
    u16* m1t   = (u16*)alloc(147456L * 2);
    u16* m2t   = (u16*)alloc(147456L * 2);
    u16* wprmb = (u16*)alloc(256L * 384 * 2);
    char* chunkBase = p;

    // per-batch ws bytes:
    // bf16: a0 768 + h1b 384 + xb 384 + xnb 384 + qpb 192 + kqvb 1152 + vT 384 + kpT 256
    //     = 3904*T*2 ; f32: Dn T*4 + kpsum 192*4 + kptvA 7*73728*4 ; bf16 kptvb 73728*2
    const long perBatch = 3904L * T * 2 + T * 4
                        + 192L * 4 + 7L * 73728 * 4 + 73728L * 2;
    const long fixed = (long)(chunkBase - (char*)d_ws) + (1L << 20);
    int nb = 2;
    for (int cand = 16; cand >= 2; cand >>= 1){
        if (fixed + (long)cand * perBatch + 128L * 1024 <= (long)ws_size){ nb = cand; break; }
    }

    const dim3 blk(256);

    wt_kernel<<<dim3((294912 + 255) / 256), blk, 0, stream>>>(W1, w1t, 768, 384, 294912);
    wt_kernel<<<dim3((147456 + 255) / 256), blk, 0, stream>>>(W2, w2t, 384, 384, 147456);
    wt_kernel<<<dim3((442368 + 255) / 256), blk, 0, stream>>>(kqv_w, kqvt, 384, 1152, 442368);
    wt_kernel<<<dim3((147456 + 255) / 256), blk, 0, stream>>>(proj_w, prjt, 384, 384, 147456);
    wt_kernel<<<dim3((147456 + 255) / 256), blk, 0, stream>>>(mlp_w1, m1t, 384, 384, 147456);
    wt_kernel<<<dim3((147456 + 255) / 256), blk, 0, stream>>>(mlp_w2, m2t, 384, 384, 147456);
    zero_kernel<<<dim3(64), blk, 0, stream>>>((float*)wprmb, 256L * 384 / 2);
    cvt_kernel<<<dim3((18432 + 255) / 256), blk, 0, stream>>>(w_prm, wprmb, 18432);

    for (int b0 = 0; b0 < 16; b0 += nb){
        const long Mc = (long)nb * T;
        const int  gy128 = (int)(Mc / 128);
        const float* i1 = in1 + (long)b0 * T * 384;
        const float* i2 = in2 + (long)b0 * T * 384;
        float* outc = out + (long)b0 * T * 384;

        p = chunkBase;
        u16*  a0    = (u16*)alloc(Mc * 768 * 2);    // concat bf16 ; later mlp hidden
        u16*  h1b   = (u16*)alloc(Mc * 384 * 2);    // h1 ; later t_att
        u16*  xb    = (u16*)alloc(Mc * 384 * 2);    // x bf16
        u16*  xnb   = (u16*)alloc(Mc * 384 * 2);    // xn ; later z
        u16*  qpb   = (u16*)alloc(Mc * 192 * 2);    // qp (followed by allocs: OOB pad)
        u16*  kqvb  = (u16*)alloc(Mc * 1152 * 2);   // fused k|q|v
        u16*  vT    = (u16*)alloc(384L * Mc * 2);   // v^T
        u16*  kpT   = (u16*)alloc(256L * Mc * 2);   // kp^T (padded rows)
        float* Dn   = (float*)alloc(Mc * 4);
        float* kpsum= (float*)alloc((long)nb * 192 * 4);
        float* kptvA= (float*)alloc((long)nb * 7 * 73728 * 4);
        u16*  kptvb = (u16*)alloc((long)nb * 73728 * 2);
        (void)alloc(128L * 1024);

        // 0) a0 = bf16(concat)
        {
            long nq = Mc * 192;
            ca_kernel<<<dim3((unsigned)((nq + 255) / 256)), blk, 0, stream>>>(i1, i2, a0, nq);
        }
        // 1) h1 = GELU(a0 @ W1t^T + b1)
        gemm_bf16<1,0,0><<<dim3(3, gy128, 1), blk, 0, stream>>>(
            a0, 768, w1t, 768, h1b, 384, b1, nullptr, nullptr, 0,
            (int)Mc, 384, 768, 1, 0,0,0,0, 0.f);
        // 2) x = h1 @ W2t^T + b2  [bf16]
        gemm_bf16<0,0,0><<<dim3(3, gy128, 1), blk, 0, stream>>>(
            h1b, 384, w2t, 384, xb, 384, b2, nullptr, nullptr, 0,
            (int)Mc, 384, 384, 1, 0,0,0,0, 0.f);
        // 3) LN1 (bf16 in) -> xn bf16
        ln_kernel<0><<<dim3((unsigned)(Mc / 4)), blk, 0, stream>>>(xb, xnb, ln1_g, ln1_b);
        // 4) kqv = xn @ kqvt^T + kqv_b  [N=1152 fused]
        gemm_bf16<0,0,0><<<dim3(9, gy128, 1), blk, 0, stream>>>(
            xnb, 384, kqvt, 384, kqvb, 1152, kqv_b, nullptr, nullptr, 0,
            (int)Mc, 1152, 384, 1, 0,0,0,0, 0.f);
        // 5) FAVOR dual: z=0 kpT (transposed), z=1 qp (row); xd computed in-GEMM
        gemm_bf16<10,0,1><<<dim3(2, gy128, 2), blk, 0, stream>>>(
            kqvb, 1152, wprmb, 384, kpT, (int)Mc, nullptr, nullptr, qpb, 192,
            (int)Mc, 192, 384, 1, 384, 0, 0, 0, prm_scale);
        // 6) kpsum from kpT rows
        kpsum2_kernel<<<dim3(nb * 48), blk, 0, stream>>>(kpT, kpsum, Mc, (int)T);
        // 7) vT = transpose of v
        trb_kernel<<<dim3(6, (unsigned)(Mc / 64)), blk, 0, stream>>>(kqvb + 768, 1152, vT, Mc);
        // 8) kptv: [384][192] = vT(b) @ kpT(b)^T, split-K=7 slices ; reduce
        gemm_bf16<8,0,1><<<dim3(2, 3, nb * 7), blk, 0, stream>>>(
            vT, (int)Mc, kpT, (int)Mc, kptvA, 192, nullptr, nullptr, nullptr, 0,
            384, 192, 3136, 7, 3136, 3136, 73728, 0, 0.f);
        kred_kernel<<<dim3((unsigned)((long)nb * 73728 / 256)), blk, 0, stream>>>(
            kptvA, kptvb, (long)nb * 73728);
        // 9) Dn
        dn_kernel<<<dim3((unsigned)(Mc / 4)), blk, 0, stream>>>(qpb, kpsum, Dn, (int)T);
        // 10) t_att = (qp @ kptv^T) / (Dn+1e-8)
        gemm_bf16<3,1,0><<<dim3(3, 25, nb), blk, 0, stream>>>(
            qpb, 192, kptvb, 192, h1b, 384, nullptr, Dn, nullptr, 0,
            (int)T, 384, 192, 1, T*192, 73728, T*384, T, 0.f);
        // 11) y = t_att @ proj + proj_b + v(bf16) -> outc f32
        gemm_bf16<9,0,0><<<dim3(3, gy128, 1), blk, 0, stream>>>(
            h1b, 384, prjt, 384, outc, 384, proj_b, nullptr, kqvb + 768, 1152,
            (int)Mc, 384, 384, 1, 0,0,0,0, 0.f);
        // 12) LN2 (f32 in) -> z bf16
        ln_kernel<1><<<dim3((unsigned)(Mc / 4)), blk, 0, stream>>>(outc, xnb, ln2_g, ln2_b);
        // 13) h = GELU(z @ mlp1 + b) -> a0
        gemm_bf16<1,0,0><<<dim3(3, gy128, 1), blk, 0, stream>>>(
            xnb, 384, m1t, 384, a0, 384, mlp_b1, nullptr, nullptr, 0,
            (int)Mc, 384, 384, 1, 0,0,0,0, 0.f);
        // 14) out = h @ mlp2 + b + y  (in-place residual)
        gemm_bf16<4,0,0><<<dim3(3, gy128, 1), blk, 0, stream>>>(
            a0, 384, m2t, 384, outc, 384, mlp_b2, nullptr, outc, 384,
            (int)Mc, 384, 384, 1, 0,0,0,0, 0.f);
    }
}

// Round 12
// 837.831 us; speedup vs baseline: 1.2043x; 1.0450x over previous
//
#include <hip/hip_runtime.h>
#include <math.h>

typedef unsigned short u16;
typedef unsigned int   u32;
typedef __attribute__((ext_vector_type(8))) short short8;
typedef __attribute__((ext_vector_type(4))) float f32x4;

typedef const void __attribute__((address_space(1))) gvoid_t;
typedef void       __attribute__((address_space(3))) svoid_t;

__device__ __forceinline__ void gload_lds16(const void* g, void* l){
    __builtin_amdgcn_global_load_lds((gvoid_t*)g, (svoid_t*)l, 16, 0, 0);
}

__device__ __forceinline__ float gelu_f(float x){
    return 0.5f * x * (1.0f + erff(x * 0.70710678118654752f));
}
__device__ __forceinline__ u16 f2b(float x){
    union{float f; u32 u;} v; v.f = x;
    u32 r = (v.u + 0x7fffu + ((v.u >> 16) & 1u)) >> 16;
    return (u16)r;
}
__device__ __forceinline__ float b2f(u16 h){
    union{u32 u; float f;} v; v.u = ((u32)h) << 16; return v.f;
}

// ===================== bf16 MFMA GEMM (frozen loop; vectorized LDS-bounce epilogue) ====
// A: bf16 [M][lda] row-major. B: bf16 [N][ldb] row-major. Tile 128x128, BK=64,
// 4 waves, XOR-swizzled LDS, global_load_lds staging w/ inverse swizzle on src,
// T1 XCD-chunked bijective block swizzle.
// Epilogue: fragments -> 128x128 LDS tile (math applied) -> coalesced 16B stores;
// residual (EPI4 f32 / EPI9 bf16) read coalesced in the store phase.
// EPI: 0:+bias->bf16  1:+bias,GELU->bf16  3:/(rowv[r]+1e-8)->bf16
//      4:+bias+resid(f32,ldr)->f32  8:plain f32 store into per-splitK slice
//      9:+bias+resid(bf16,ldr)->f32
//      10:FAVOR dual (in-GEMM xd): z==0 TRANSPOSED kpT store (custom);
//         z==1 row store of qp via bounce to resid(ldr). A += z*sA.
template<int EPI, int GUARD, int CGUARD>
__global__ __launch_bounds__(256)
void gemm_bf16(const u16* __restrict__ A, int lda,
               const u16* __restrict__ B, int ldb,
               void* __restrict__ Cv, int ldc,
               const float* __restrict__ bias,
               const float* __restrict__ rowv,
               void* __restrict__ resid, int ldr,
               int Mrows, int Ncols, int K, int splitK,
               long sA, long sB, long sC, long sRV,
               float scale)
{
    const int bz = blockIdx.z;
    const int b  = bz / splitK, kc = bz % splitK;
    A += (long)b * sA;  B += (long)b * sB;
    const float* rv = (EPI == 3) ? rowv + (long)b * sRV : nullptr;

    __shared__ u16 SMEM[32768];     // 64KB: dbuf tiles during loop, C-tile in epilogue
    __shared__ float xds[128];      // EPI10: per-row 0.5*||a||^2
    u16* const As0 = SMEM;
    u16* const Bs0 = SMEM + 8192;
    u16* const As1 = SMEM + 16384;
    u16* const Bs1 = SMEM + 24576;

    const int tid = threadIdx.x;

    // T1 XCD-chunked bijective swizzle (within z-slice)
    const int gx  = gridDim.x;
    const int nwg = gx * gridDim.y;
    const int L   = blockIdx.y * gx + blockIdx.x;
    const int q8  = nwg >> 3, r8 = nwg & 7;
    const int xc  = L & 7,   i8 = L >> 3;
    const int nid = (xc < r8 ? xc * (q8 + 1) : r8 * (q8 + 1) + (xc - r8) * q8) + i8;
    const int row0 = (nid / gx) * 128, col0 = (nid % gx) * 128;

    f32x4 acc[4][4] = {};
    float sqacc[4] = {0.f, 0.f, 0.f, 0.f};

    const int l  = tid & 63, w4 = tid >> 6;
    const int wr = w4 >> 1, wc = w4 & 1;
    const int g  = l >> 4,  mr = l & 15;

    const int kLen   = K / splitK;
    const int kStart = kc * kLen;
    const int nt     = kLen / 64;

    const int m0   = w4 * 8 + (l >> 3);
    const int k8s  = (l & 7) ^ (m0 & 7);
    const int lBase = w4 * 512 + l * 8;
    const u16* gA0 = A + (long)(row0 + m0) * lda + kStart + k8s * 8;
    const u16* gB0 = B + (long)(col0 + m0) * ldb + kStart + k8s * 8;

    int aOff[4], bOff[4], sl[2];
    #pragma unroll
    for (int i = 0; i < 4; i++){
        aOff[i] = (wr * 64 + i * 16 + mr) * 64;
        bOff[i] = (wc * 64 + i * 16 + mr) * 64;
    }
    #pragma unroll
    for (int kk = 0; kk < 2; kk++)
        sl[kk] = (((kk * 4 + g) ^ (mr & 7)) & 7) * 8;

#define STAGE(AS, BS, KOFF)                                             \
    {                                                                   \
        _Pragma("unroll")                                               \
        for (int q = 0; q < 4; q++){                                    \
            gload_lds16(gA0 + (long)q * 32 * lda + (KOFF), &(AS)[lBase + q * 2048]); \
            gload_lds16(gB0 + (long)q * 32 * ldb + (KOFF), &(BS)[lBase + q * 2048]); \
        }                                                               \
    }

#define COMPUTE(AS, BS)                                                 \
    {                                                                   \
        short8 af[2][4], bfr[2][4];                                     \
        _Pragma("unroll")                                               \
        for (int kk = 0; kk < 2; kk++){                                 \
            _Pragma("unroll")                                           \
            for (int i = 0; i < 4; i++){                                \
                af[kk][i]  = *(const short8*)&(AS)[aOff[i] + sl[kk]];   \
                bfr[kk][i] = *(const short8*)&(BS)[bOff[i] + sl[kk]];   \
            }                                                           \
        }                                                               \
        if (EPI == 10){                                                 \
            _Pragma("unroll")                                           \
            for (int kk = 0; kk < 2; kk++)                              \
                _Pragma("unroll")                                       \
                for (int i = 0; i < 4; i++)                             \
                    _Pragma("unroll")                                   \
                    for (int e = 0; e < 8; e++){                        \
                        float f_ = b2f((u16)af[kk][i][e]);              \
                        sqacc[i] += f_ * f_;                            \
                    }                                                   \
        }                                                               \
        _Pragma("unroll")                                               \
        for (int kk = 0; kk < 2; kk++)                                  \
            _Pragma("unroll")                                           \
            for (int i = 0; i < 4; i++)                                 \
                _Pragma("unroll")                                       \
                for (int j = 0; j < 4; j++)                             \
                    acc[i][j] = __builtin_amdgcn_mfma_f32_16x16x32_bf16(af[kk][i], bfr[kk][j], acc[i][j], 0, 0, 0); \
    }

    STAGE(As0, Bs0, 0);

    for (int t = 0; t < nt; ){
        __syncthreads();
        if (t + 1 < nt) STAGE(As1, Bs1, (t + 1) * 64);
        COMPUTE(As0, Bs0);
        t++;
        if (t >= nt) break;
        __syncthreads();
        if (t + 1 < nt) STAGE(As0, Bs0, (t + 1) * 64);
        COMPUTE(As1, Bs1);
        t++;
    }
#undef STAGE
#undef COMPUTE

    if (EPI == 10){
        // reduce Sum(a^2) across the 4 g-lane groups (lanes differ in bits 4,5)
        #pragma unroll
        for (int i = 0; i < 4; i++){
            float s = sqacc[i];
            s += __shfl_xor(s, 16);
            s += __shfl_xor(s, 32);
            if (l < 16) xds[wr * 64 + i * 16 + l] = 0.5f * s;
        }
    }
    __syncthreads();   // all LDS reads of the K-loop done; xds visible (EPI10)

    float* Cf = (float*)Cv + (EPI == 8 ? (long)bz : (long)b) * sC;
    u16*   Cb = (u16*)Cv   + (EPI == 10 ? 0L : (long)b * sC);

    if (EPI == 10 && bz == 0){
        // custom transposed kpT store (8B-packed column writes)
        #pragma unroll
        for (int i = 0; i < 4; i++){
            #pragma unroll
            for (int j = 0; j < 4; j++){
                const int col = col0 + wc * 64 + j * 16 + mr;
                if (CGUARD && col >= Ncols) continue;
                const int lrow = wr * 64 + i * 16 + g * 4;
                u16 pk[4];
                #pragma unroll
                for (int r = 0; r < 4; r++)
                    pk[r] = f2b(expf(acc[i][j][r] - xds[lrow + r]) * scale);
                *(ushort4*)&Cb[(long)col * ldc + row0 + lrow] = *(ushort4*)pk;
            }
        }
        return;
    }

    // ---- bounce epilogue: fragments -> LDS tile (math applied) ----
    constexpr bool OUTF32 = (EPI == 4 || EPI == 8 || EPI == 9);
    float* const Sf = (float*)SMEM;
    #pragma unroll
    for (int i = 0; i < 4; i++){
        #pragma unroll
        for (int j = 0; j < 4; j++){
            const int cl = wc * 64 + j * 16 + mr;
            const float bv = (EPI == 0 || EPI == 1 || EPI == 4 || EPI == 9)
                           ? bias[col0 + cl] : 0.f;
            #pragma unroll
            for (int r = 0; r < 4; r++){
                const int rl = wr * 64 + i * 16 + g * 4 + r;
                float vv = acc[i][j][r];
                if      (EPI == 1)  vv = gelu_f(vv + bv);
                else if (EPI == 3)  vv = vv / (rv[row0 + rl] + 1e-8f);
                else if (EPI == 10) vv = expf(vv - xds[rl]) * scale;
                else                vv += bv;   // EPI 0,4,9 (+0 for 8)
                if (OUTF32) Sf[rl * 128 + cl] = vv;
                else        SMEM[rl * 128 + cl] = f2b(vv);
            }
        }
    }
    __syncthreads();

    // ---- coalesced store phase (+ coalesced residual read for EPI4/9) ----
    if (OUTF32){
        #pragma unroll
        for (int s = 0; s < 16; s++){
            const int qi = s * 256 + tid;
            const int rl = qi >> 5, c4 = (qi & 31) << 2;
            const int row = row0 + rl, col = col0 + c4;
            if (GUARD && row >= Mrows) continue;
            if (CGUARD && col >= Ncols) continue;
            float4 v = *(float4*)&Sf[rl * 128 + c4];
            if (EPI == 4){
                float4 rr = *(const float4*)&((const float*)resid)[(long)row * ldr + col];
                v.x += rr.x; v.y += rr.y; v.z += rr.z; v.w += rr.w;
            } else if (EPI == 9){
                ushort4 rh = *(const ushort4*)&((const u16*)resid)[(long)row * ldr + col];
                v.x += b2f(rh.x); v.y += b2f(rh.y); v.z += b2f(rh.z); v.w += b2f(rh.w);
            }
            *(float4*)&Cf[(long)row * ldc + col] = v;
        }
    } else {
        u16* dst; long ld;
        if (EPI == 10){ dst = (u16*)resid; ld = ldr; }
        else          { dst = Cb;          ld = ldc; }
        #pragma unroll
        for (int s = 0; s < 8; s++){
            const int oi = s * 256 + tid;
            const int rl = oi >> 4, c8 = (oi & 15) << 3;
            const int row = row0 + rl, col = col0 + c8;
            if (GUARD && row >= Mrows) continue;
            if (CGUARD && col >= Ncols) continue;
            *(uint4*)&dst[(long)row * ld + col] = *(uint4*)&SMEM[rl * 128 + c8];
        }
    }
}

// bf16 strided transpose: out[(cb+c)*R + rb+r] = in[(rb+r)*inStride + cb+c]
__global__ __launch_bounds__(256)
void trb_kernel(const u16* __restrict__ in, long inStride, u16* __restrict__ out, long R)
{
    __shared__ u16 t[64][72];
    const long cb = (long)blockIdx.x * 64, rb = (long)blockIdx.y * 64;
    const int tl = threadIdx.x & 63, tw = threadIdx.x >> 6;
    #pragma unroll
    for (int i = 0; i < 16; i++){
        const int r = tw + i * 4;
        t[r][tl] = in[(rb + r) * inStride + cb + tl];
    }
    __syncthreads();
    #pragma unroll
    for (int i = 0; i < 16; i++){
        const int c = tw + i * 4;
        out[(cb + c) * R + rb + tl] = t[tl][c];
    }
}

__global__ __launch_bounds__(256)
void kred_kernel(const float* __restrict__ in, u16* __restrict__ out, long n)
{
    long idx = (long)blockIdx.x * 256 + threadIdx.x;
    if (idx >= n) return;
    const long b = idx / 73728, r = idx - b * 73728;
    const float* s = in + b * 7 * 73728L + r;
    float acc = 0.f;
    #pragma unroll
    for (int kc = 0; kc < 7; kc++) acc += s[kc * 73728L];
    out[idx] = f2b(acc);
}

// LayerNorm over D=384; input f32 (INF32=1) or bf16 (INF32=0); bf16 out.
template<int INF32>
__global__ __launch_bounds__(256)
void ln_kernel(const void* __restrict__ xv, u16* __restrict__ ob,
               const float* __restrict__ g, const float* __restrict__ bta)
{
    const int lane = threadIdx.x & 63;
    const long r = (long)blockIdx.x * 4 + (threadIdx.x >> 6);
    float v[6]; float s = 0.f;
    #pragma unroll
    for (int i = 0; i < 6; i++){
        const int c = lane + i * 64;
        v[i] = INF32 ? ((const float*)xv)[r * 384 + c]
                     : b2f(((const u16*)xv)[r * 384 + c]);
        s += v[i];
    }
    #pragma unroll
    for (int off = 32; off; off >>= 1) s += __shfl_xor(s, off);
    const float mu = s * (1.0f/384.0f);
    float q = 0.f;
    #pragma unroll
    for (int i = 0; i < 6; i++){ float d = v[i] - mu; q += d*d; }
    #pragma unroll
    for (int off = 32; off; off >>= 1) q += __shfl_xor(q, off);
    const float inv = rsqrtf(q * (1.0f/384.0f) + 1e-5f);
    #pragma unroll
    for (int i = 0; i < 6; i++){
        const int c = lane + i*64;
        ob[r * 384 + c] = f2b((v[i] - mu) * inv * g[c] + bta[c]);
    }
}

// Dn[r] = dot(qp_bf16[r,:192], kpsum[r/T,:192])
__global__ __launch_bounds__(256)
void dn_kernel(const u16* __restrict__ qp, const float* __restrict__ kpsum,
               float* __restrict__ Dn, int T)
{
    const int lane = threadIdx.x & 63;
    const long r = (long)blockIdx.x * 4 + (threadIdx.x >> 6);
    const int b = (int)(r / T);
    const u16* qr = qp + r * 192;
    const float* ks = kpsum + (long)b * 192;
    float s = 0.f;
    #pragma unroll
    for (int i = 0; i < 3; i++){ const int m = lane + i*64; s += b2f(qr[m]) * ks[m]; }
    #pragma unroll
    for (int off = 32; off; off >>= 1) s += __shfl_xor(s, off);
    if (lane == 0) Dn[r] = s;
}

// kpsum[bl][m] = sum_t kpT[m][bl*T + t]
__global__ __launch_bounds__(256)
void kpsum2_kernel(const u16* __restrict__ kpT, float* __restrict__ kpsum, long Mc, int T)
{
    const int lane = threadIdx.x & 63;
    const int gw = blockIdx.x * 4 + (threadIdx.x >> 6);
    const int m = gw % 192, bl = gw / 192;
    const u16* row = kpT + (long)m * Mc + (long)bl * T;
    float s = 0.f;
    for (int i = lane; i < T; i += 64) s += b2f(row[i]);
    #pragma unroll
    for (int off = 32; off; off >>= 1) s += __shfl_xor(s, off);
    if (lane == 0) kpsum[bl * 192 + m] = s;
}

__global__ __launch_bounds__(256)
void zero_kernel(float* __restrict__ p, long n)
{
    long i = (long)blockIdx.x * 256 + threadIdx.x;
    long stride = (long)gridDim.x * 256;
    for (; i < n; i += stride) p[i] = 0.f;
}

// concat(in1,in2) row-major -> bf16 [Mc][768]
__global__ __launch_bounds__(256)
void ca_kernel(const float* __restrict__ i1, const float* __restrict__ i2,
               u16* __restrict__ a0, long nquad)
{
    long idx = (long)blockIdx.x * 256 + threadIdx.x;
    if (idx >= nquad) return;
    const long r = idx / 192;
    const int  c0 = (int)(idx % 192) * 4;
    const float* src = (c0 < 384) ? &i1[r * 384 + c0] : &i2[r * 384 + (c0 - 384)];
    float4 v = *(const float4*)src;
    u32 w0 = (u32)f2b(v.x) | ((u32)f2b(v.y) << 16);
    u32 w1 = (u32)f2b(v.z) | ((u32)f2b(v.w) << 16);
    *(uint2*)&a0[r * 768 + c0] = make_uint2(w0, w1);
}

// wt[n*K + k] = bf16(w[k*N + n])
__global__ __launch_bounds__(256)
void wt_kernel(const float* __restrict__ w, u16* __restrict__ wt, int K, int N, long total)
{
    long idx = (long)blockIdx.x * 256 + threadIdx.x;
    if (idx >= total) return;
    const long n = idx / K, k = idx - n * K;
    wt[idx] = f2b(w[k * N + n]);
}

// flat f32 -> bf16
__global__ __launch_bounds__(256)
void cvt_kernel(const float* __restrict__ s, u16* __restrict__ d, long n4)
{
    long idx = (long)blockIdx.x * 256 + threadIdx.x;
    if (idx >= n4) return;
    float4 v = *(const float4*)&s[idx * 4];
    u32 w0 = (u32)f2b(v.x) | ((u32)f2b(v.y) << 16);
    u32 w1 = (u32)f2b(v.z) | ((u32)f2b(v.w) << 16);
    *(uint2*)&d[idx * 4] = make_uint2(w0, w1);
}

extern "C" void kernel_launch(void* const* d_in, const int* in_sizes, int n_in,
                              void* d_out, int out_size, void* d_ws, size_t ws_size,
                              hipStream_t stream)
{
    const long T = 3136;
    const float prm_scale = 0.07216878364870322f;  // 1/sqrt(192)

    const float* in1    = (const float*)d_in[0];
    const float* in2    = (const float*)d_in[1];
    const float* W1     = (const float*)d_in[2];
    const float* b1     = (const float*)d_in[3];
    const float* W2     = (const float*)d_in[4];
    const float* b2     = (const float*)d_in[5];
    const float* kqv_w  = (const float*)d_in[6];
    const float* kqv_b  = (const float*)d_in[7];
    const float* proj_w = (const float*)d_in[8];
    const float* proj_b = (const float*)d_in[9];
    const float* ln1_g  = (const float*)d_in[10];
    const float* ln1_b  = (const float*)d_in[11];
    const float* ln2_g  = (const float*)d_in[12];
    const float* ln2_b  = (const float*)d_in[13];
    const float* mlp_w1 = (const float*)d_in[14];
    const float* mlp_b1 = (const float*)d_in[15];
    const float* mlp_w2 = (const float*)d_in[16];
    const float* mlp_b2 = (const float*)d_in[17];
    const float* w_prm  = (const float*)d_in[18];
    float* out = (float*)d_out;

    char* p = (char*)d_ws;
    auto alloc = [&](long bytes)->char*{ char* r = p; p += (bytes + 255) & ~255L; return r; };

    // chunk-invariant bf16 weights
    u16* w1t   = (u16*)alloc(294912L * 2);
    u16* w2t   = (u16*)alloc(147456L * 2);
    u16* kqvt  = (u16*)alloc(442368L * 2);
    u16* prjt  = (u16*)alloc(147456L * 2);
    u16* m1t   = (u16*)alloc(147456L * 2);
    u16* m2t   = (u16*)alloc(147456L * 2);
    u16* wprmb = (u16*)alloc(256L * 384 * 2);
    char* chunkBase = p;

    // per-batch ws bytes (see allocs below)
    const long perBatch = 3904L * T * 2 + T * 4
                        + 192L * 4 + 7L * 73728 * 4 + 73728L * 2;
    const long fixed = (long)(chunkBase - (char*)d_ws) + (1L << 20);
    int nb = 2;
    for (int cand = 16; cand >= 2; cand >>= 1){
        if (fixed + (long)cand * perBatch + 128L * 1024 <= (long)ws_size){ nb = cand; break; }
    }

    const dim3 blk(256);

    wt_kernel<<<dim3((294912 + 255) / 256), blk, 0, stream>>>(W1, w1t, 768, 384, 294912);
    wt_kernel<<<dim3((147456 + 255) / 256), blk, 0, stream>>>(W2, w2t, 384, 384, 147456);
    wt_kernel<<<dim3((442368 + 255) / 256), blk, 0, stream>>>(kqv_w, kqvt, 384, 1152, 442368);
    wt_kernel<<<dim3((147456 + 255) / 256), blk, 0, stream>>>(proj_w, prjt, 384, 384, 147456);
    wt_kernel<<<dim3((147456 + 255) / 256), blk, 0, stream>>>(mlp_w1, m1t, 384, 384, 147456);
    wt_kernel<<<dim3((147456 + 255) / 256), blk, 0, stream>>>(mlp_w2, m2t, 384, 384, 147456);
    zero_kernel<<<dim3(64), blk, 0, stream>>>((float*)wprmb, 256L * 384 / 2);
    cvt_kernel<<<dim3((18432 + 255) / 256), blk, 0, stream>>>(w_prm, wprmb, 18432);

    for (int b0 = 0; b0 < 16; b0 += nb){
        const long Mc = (long)nb * T;
        const int  gy128 = (int)(Mc / 128);
        const float* i1 = in1 + (long)b0 * T * 384;
        const float* i2 = in2 + (long)b0 * T * 384;
        float* outc = out + (long)b0 * T * 384;

        p = chunkBase;
        u16*  a0    = (u16*)alloc(Mc * 768 * 2);    // concat bf16 ; later mlp hidden
        u16*  h1b   = (u16*)alloc(Mc * 384 * 2);    // h1 ; later t_att
        u16*  xb    = (u16*)alloc(Mc * 384 * 2);    // x bf16
        u16*  xnb   = (u16*)alloc(Mc * 384 * 2);    // xn ; later z
        u16*  qpb   = (u16*)alloc(Mc * 192 * 2);    // qp (followed by allocs: OOB pad)
        u16*  kqvb  = (u16*)alloc(Mc * 1152 * 2);   // fused k|q|v
        u16*  vT    = (u16*)alloc(384L * Mc * 2);   // v^T
        u16*  kpT   = (u16*)alloc(256L * Mc * 2);   // kp^T (padded rows)
        float* Dn   = (float*)alloc(Mc * 4);
        float* kpsum= (float*)alloc((long)nb * 192 * 4);
        float* kptvA= (float*)alloc((long)nb * 7 * 73728 * 4);
        u16*  kptvb = (u16*)alloc((long)nb * 73728 * 2);
        (void)alloc(128L * 1024);

        // 0) a0 = bf16(concat)
        {
            long nq = Mc * 192;
            ca_kernel<<<dim3((unsigned)((nq + 255) / 256)), blk, 0, stream>>>(i1, i2, a0, nq);
        }
        // 1) h1 = GELU(a0 @ W1t^T + b1)
        gemm_bf16<1,0,0><<<dim3(3, gy128, 1), blk, 0, stream>>>(
            a0, 768, w1t, 768, h1b, 384, b1, nullptr, nullptr, 0,
            (int)Mc, 384, 768, 1, 0,0,0,0, 0.f);
        // 2) x = h1 @ W2t^T + b2  [bf16]
        gemm_bf16<0,0,0><<<dim3(3, gy128, 1), blk, 0, stream>>>(
            h1b, 384, w2t, 384, xb, 384, b2, nullptr, nullptr, 0,
            (int)Mc, 384, 384, 1, 0,0,0,0, 0.f);
        // 3) LN1 (bf16 in) -> xn bf16
        ln_kernel<0><<<dim3((unsigned)(Mc / 4)), blk, 0, stream>>>(xb, xnb, ln1_g, ln1_b);
        // 4) kqv = xn @ kqvt^T + kqv_b  [N=1152 fused]
        gemm_bf16<0,0,0><<<dim3(9, gy128, 1), blk, 0, stream>>>(
            xnb, 384, kqvt, 384, kqvb, 1152, kqv_b, nullptr, nullptr, 0,
            (int)Mc, 1152, 384, 1, 0,0,0,0, 0.f);
        // 5) FAVOR dual: z=0 kpT (transposed), z=1 qp (row); xd computed in-GEMM
        gemm_bf16<10,0,1><<<dim3(2, gy128, 2), blk, 0, stream>>>(
            kqvb, 1152, wprmb, 384, kpT, (int)Mc, nullptr, nullptr, qpb, 192,
            (int)Mc, 192, 384, 1, 384, 0, 0, 0, prm_scale);
        // 6) kpsum from kpT rows
        kpsum2_kernel<<<dim3(nb * 48), blk, 0, stream>>>(kpT, kpsum, Mc, (int)T);
        // 7) vT = transpose of v
        trb_kernel<<<dim3(6, (unsigned)(Mc / 64)), blk, 0, stream>>>(kqvb + 768, 1152, vT, Mc);
        // 8) kptv: [384][192] = vT(b) @ kpT(b)^T, split-K=7 slices ; reduce
        gemm_bf16<8,0,1><<<dim3(2, 3, nb * 7), blk, 0, stream>>>(
            vT, (int)Mc, kpT, (int)Mc, kptvA, 192, nullptr, nullptr, nullptr, 0,
            384, 192, 3136, 7, 3136, 3136, 73728, 0, 0.f);
        kred_kernel<<<dim3((unsigned)((long)nb * 73728 / 256)), blk, 0, stream>>>(
            kptvA, kptvb, (long)nb * 73728);
        // 9) Dn
        dn_kernel<<<dim3((unsigned)(Mc / 4)), blk, 0, stream>>>(qpb, kpsum, Dn, (int)T);
        // 10) t_att = (qp @ kptv^T) / (Dn+1e-8)
        gemm_bf16<3,1,0><<<dim3(3, 25, nb), blk, 0, stream>>>(
            qpb, 192, kptvb, 192, h1b, 384, nullptr, Dn, nullptr, 0,
            (int)T, 384, 192, 1, T*192, 73728, T*384, T, 0.f);
        // 11) y = t_att @ proj + proj_b + v(bf16) -> outc f32
        gemm_bf16<9,0,0><<<dim3(3, gy128, 1), blk, 0, stream>>>(
            h1b, 384, prjt, 384, outc, 384, proj_b, nullptr, kqvb + 768, 1152,
            (int)Mc, 384, 384, 1, 0,0,0,0, 0.f);
        // 12) LN2 (f32 in) -> z bf16
        ln_kernel<1><<<dim3((unsigned)(Mc / 4)), blk, 0, stream>>>(outc, xnb, ln2_g, ln2_b);
        // 13) h = GELU(z @ mlp1 + b) -> a0
        gemm_bf16<1,0,0><<<dim3(3, gy128, 1), blk, 0, stream>>>(
            xnb, 384, m1t, 384, a0, 384, mlp_b1, nullptr, nullptr, 0,
            (int)Mc, 384, 384, 1, 0,0,0,0, 0.f);
        // 14) out = h @ mlp2 + b + y  (in-place residual)
        gemm_bf16<4,0,0><<<dim3(3, gy128, 1), blk, 0, stream>>>(
            a0, 384, m2t, 384, outc, 384, mlp_b2, nullptr, outc, 384,
            (int)Mc, 384, 384, 1, 0,0,0,0, 0.f);
    }
}